// Round 1
// baseline (277.300 us; speedup 1.0000x reference)
//
#include <hip/hip_runtime.h>

#define BB 4
#define CIN 128
#define T3 384
#define HH 128
#define WW 128
#define NPIX 16384
#define QKV_ELE (BB*T3*NPIX)   // 25165824 floats per big buffer

// ============================================================================
// K1: qkv[b,co,n] = sum_ci wqkv[co,ci] * x[b,ci,n]   (GEMM 384x128 @ 128x16384)
// Tile: 128co x 128n, K-chunks of 32. 8x8 acc per thread, 256 threads.
// ============================================================================
__global__ __launch_bounds__(256) void k1_qkv(const float* __restrict__ x,
                                              const float* __restrict__ wqkv,
                                              float* __restrict__ qkv) {
  __shared__ __align__(16) float As[32 * 128];  // [k][co] (transposed weights)
  __shared__ __align__(16) float Bs[32 * 128];  // [k][n]
  const int t = threadIdx.x;
  const int n0 = blockIdx.x * 128;
  const int co0 = blockIdx.y * 128;
  const int b = blockIdx.z;
  const float* xb = x + (size_t)b * CIN * NPIX;

  float acc[8][8];
  #pragma unroll
  for (int i = 0; i < 8; ++i)
    #pragma unroll
    for (int j = 0; j < 8; ++j) acc[i][j] = 0.f;

  const int co_g = t >> 4;   // 0..15 -> co = co0 + co_g*8 + i
  const int n_g = t & 15;    // 0..15 -> n  = n0  + n_g*8  + j

  for (int k0 = 0; k0 < CIN; k0 += 32) {
    {  // stage A transposed: As[k][co]
      const int co_l = t >> 1;       // 0..127
      const int kq = t & 1;          // 0..1
      const float* mrow = wqkv + (size_t)(co0 + co_l) * CIN + k0 + kq * 16;
      #pragma unroll
      for (int r = 0; r < 4; ++r) {
        float4 v = ((const float4*)mrow)[r];
        int k = kq * 16 + r * 4;
        As[(k + 0) * 128 + co_l] = v.x;
        As[(k + 1) * 128 + co_l] = v.y;
        As[(k + 2) * 128 + co_l] = v.z;
        As[(k + 3) * 128 + co_l] = v.w;
      }
    }
    {  // stage B: Bs[k][n]
      const int k_l = t >> 3;        // 0..31
      const int nq = t & 7;          // 0..7
      const float* xrow = xb + (size_t)(k0 + k_l) * NPIX + n0 + nq * 16;
      float4 v0 = ((const float4*)xrow)[0];
      float4 v1 = ((const float4*)xrow)[1];
      float4 v2 = ((const float4*)xrow)[2];
      float4 v3 = ((const float4*)xrow)[3];
      float* brow = &Bs[k_l * 128 + nq * 16];
      ((float4*)brow)[0] = v0;
      ((float4*)brow)[1] = v1;
      ((float4*)brow)[2] = v2;
      ((float4*)brow)[3] = v3;
    }
    __syncthreads();
    #pragma unroll
    for (int kk = 0; kk < 32; ++kk) {
      float4 a0 = *(const float4*)&As[kk * 128 + co_g * 8];
      float4 a1 = *(const float4*)&As[kk * 128 + co_g * 8 + 4];
      float4 b0 = *(const float4*)&Bs[kk * 128 + n_g * 8];
      float4 b1 = *(const float4*)&Bs[kk * 128 + n_g * 8 + 4];
      float av[8] = {a0.x, a0.y, a0.z, a0.w, a1.x, a1.y, a1.z, a1.w};
      float bv[8] = {b0.x, b0.y, b0.z, b0.w, b1.x, b1.y, b1.z, b1.w};
      #pragma unroll
      for (int i = 0; i < 8; ++i)
        #pragma unroll
        for (int j = 0; j < 8; ++j) acc[i][j] += av[i] * bv[j];
    }
    __syncthreads();
  }
  float* ob = qkv + (size_t)b * T3 * NPIX;
  #pragma unroll
  for (int i = 0; i < 8; ++i) {
    float* orow = ob + (size_t)(co0 + co_g * 8 + i) * NPIX + n0 + n_g * 8;
    float4 o0 = make_float4(acc[i][0], acc[i][1], acc[i][2], acc[i][3]);
    float4 o1 = make_float4(acc[i][4], acc[i][5], acc[i][6], acc[i][7]);
    ((float4*)orow)[0] = o0;
    ((float4*)orow)[1] = o1;
  }
}

// ============================================================================
// K2: agg = grouped_pw( dw5x5(qkv) ).  One block = (b, pw-group g of 8 ch,
// 32x16 pixel tile). dw is register-blocked 4x4 per thread.
// ============================================================================
__global__ __launch_bounds__(256) void k2_dwpw(const float* __restrict__ qkv,
                                               const float* __restrict__ wdw,
                                               const float* __restrict__ wpw,
                                               float* __restrict__ agg) {
  __shared__ __align__(16) float ins[8 * 20 * 36];  // [ch][ry 0..19][rx 0..35]
  __shared__ float wds[8][25];
  __shared__ float wps[64];
  __shared__ __align__(16) float dws[8 * 16 * 32];  // [ch][y][x]
  const int t = threadIdx.x;
  const int x0 = blockIdx.x * 32;
  const int y0 = blockIdx.y * 16;
  const int bg = blockIdx.z;       // 0..191
  const int b = bg / 48;
  const int g = bg % 48;
  const float* src = qkv + ((size_t)b * T3 + g * 8) * NPIX;

  for (int idx = t; idx < 8 * 20 * 36; idx += 256) {
    int ch = idx / 720;
    int rem = idx - ch * 720;
    int ry = rem / 36;
    int rx = rem - ry * 36;
    int gy = y0 + ry - 2;
    int gx = x0 + rx - 2;
    float v = 0.f;
    if ((unsigned)gy < HH && (unsigned)gx < WW)
      v = src[(size_t)ch * NPIX + gy * WW + gx];
    ins[idx] = v;
  }
  for (int idx = t; idx < 200; idx += 256)
    wds[idx / 25][idx % 25] = wdw[(size_t)g * 200 + idx];
  if (t < 64) wps[t] = wpw[g * 64 + t];
  __syncthreads();

  // depthwise 5x5: thread -> (ch, 4x-cols, 4y-rows)
  const int ch = t >> 5;          // 0..7
  const int xq = t & 7;           // 0..7 -> X = xq*4 + jx
  const int yg = (t >> 3) & 3;    // 0..3 -> y = yg*4 + jy
  float rbw[8][8];
  {
    const float* base = &ins[ch * 720 + (yg * 4) * 36 + xq * 4];
    #pragma unroll
    for (int r = 0; r < 8; ++r) {
      float4 u0 = *(const float4*)(base + r * 36);
      float4 u1 = *(const float4*)(base + r * 36 + 4);
      rbw[r][0] = u0.x; rbw[r][1] = u0.y; rbw[r][2] = u0.z; rbw[r][3] = u0.w;
      rbw[r][4] = u1.x; rbw[r][5] = u1.y; rbw[r][6] = u1.z; rbw[r][7] = u1.w;
    }
  }
  float dacc[4][4];
  #pragma unroll
  for (int jy = 0; jy < 4; ++jy)
    #pragma unroll
    for (int jx = 0; jx < 4; ++jx) dacc[jy][jx] = 0.f;
  #pragma unroll
  for (int ky = 0; ky < 5; ++ky)
    #pragma unroll
    for (int kx = 0; kx < 5; ++kx) {
      float wv = wds[ch][ky * 5 + kx];
      #pragma unroll
      for (int jy = 0; jy < 4; ++jy)
        #pragma unroll
        for (int jx = 0; jx < 4; ++jx)
          dacc[jy][jx] += wv * rbw[jy + ky][jx + kx];
    }
  #pragma unroll
  for (int jy = 0; jy < 4; ++jy) {
    float4 o = make_float4(dacc[jy][0], dacc[jy][1], dacc[jy][2], dacc[jy][3]);
    *(float4*)&dws[ch * 512 + (yg * 4 + jy) * 32 + xq * 4] = o;
  }
  __syncthreads();

  // grouped pointwise 8x8
  float* dst = agg + ((size_t)b * T3 + g * 8) * NPIX + (size_t)y0 * WW + x0;
  #pragma unroll
  for (int pp = 0; pp < 2; ++pp) {
    int p = t + pp * 256;      // 0..511
    int py = p >> 5;
    int px = p & 31;
    float dv[8];
    #pragma unroll
    for (int ic = 0; ic < 8; ++ic) dv[ic] = dws[ic * 512 + py * 32 + px];
    #pragma unroll
    for (int oc = 0; oc < 8; ++oc) {
      float s = 0.f;
      #pragma unroll
      for (int ic = 0; ic < 8; ++ic) s += wps[oc * 8 + ic] * dv[ic];
      dst[(size_t)oc * NPIX + py * WW + px] = s;
    }
  }
}

// ============================================================================
// K3: vk partials. block=(chunk, bh); 4 waves: wave w owns d rows {2w,2w+1},
// wave 0 also d=8 (k-colsum). Deterministic (no atomics): shuffle-reduce then
// one write per wave; k3b sums the 4 chunks.
// ============================================================================
__global__ __launch_bounds__(256) void k3_vk(const float* __restrict__ qkv,
                                             const float* __restrict__ agg,
                                             float* __restrict__ part) {
  const int chunk = blockIdx.x;  // 0..3
  const int bh = blockIdx.y;     // 0..127
  const int b = bh >> 5;
  const int h = bh & 31;
  const int hh = h & 15;
  const float* base = (h < 16 ? qkv : agg) + ((size_t)b * T3 + hh * 24) * NPIX;
  const float* kb = base + 8 * NPIX;
  const float* vb = base + 16 * NPIX;
  const int t = threadIdx.x;
  const int wv = t >> 6;
  const int lane = t & 63;
  const int d0 = wv * 2;

  float accA[8], accB[8], accS[8];
  #pragma unroll
  for (int e = 0; e < 8; ++e) { accA[e] = 0.f; accB[e] = 0.f; accS[e] = 0.f; }

  int p = chunk * 4096 + lane;
  for (int it = 0; it < 64; ++it, p += 64) {
    float kvv[8];
    #pragma unroll
    for (int e = 0; e < 8; ++e) kvv[e] = fmaxf(kb[(size_t)e * NPIX + p], 0.f);
    float vA = vb[(size_t)d0 * NPIX + p];
    float vB = vb[(size_t)(d0 + 1) * NPIX + p];
    #pragma unroll
    for (int e = 0; e < 8; ++e) { accA[e] += vA * kvv[e]; accB[e] += vB * kvv[e]; }
    if (wv == 0) {
      #pragma unroll
      for (int e = 0; e < 8; ++e) accS[e] += kvv[e];
    }
  }
  #pragma unroll
  for (int e = 0; e < 8; ++e) {
    #pragma unroll
    for (int m = 1; m < 64; m <<= 1) {
      accA[e] += __shfl_xor(accA[e], m);
      accB[e] += __shfl_xor(accB[e], m);
    }
  }
  if (wv == 0) {
    #pragma unroll
    for (int e = 0; e < 8; ++e)
      #pragma unroll
      for (int m = 1; m < 64; m <<= 1) accS[e] += __shfl_xor(accS[e], m);
  }
  if (lane == 0) {
    float* pr = part + ((size_t)bh * 4 + chunk) * 72;
    #pragma unroll
    for (int e = 0; e < 8; ++e) {
      pr[d0 * 8 + e] = accA[e];
      pr[(d0 + 1) * 8 + e] = accB[e];
    }
    if (wv == 0) {
      #pragma unroll
      for (int e = 0; e < 8; ++e) pr[64 + e] = accS[e];
    }
  }
}

__global__ __launch_bounds__(128) void k3b_sum(const float* __restrict__ part,
                                               float* __restrict__ vk) {
  const int bh = blockIdx.x;
  const int j = threadIdx.x;
  if (j < 72) {
    float s = 0.f;
    #pragma unroll
    for (int c = 0; c < 4; ++c) s += part[((size_t)bh * 4 + c) * 72 + j];
    vk[(size_t)bh * 72 + j] = s;
  }
}

// ============================================================================
// K3c: M'[b][co][8h+e] = inv[co] * sum_d Wp[co][8h+d] * vk[b,h,d,e];
//      shift[co] = beta - mean*inv   (BN folded)
// ============================================================================
__global__ __launch_bounds__(256) void k3c_M(const float* __restrict__ wproj,
                                             const float* __restrict__ vk,
                                             const float* __restrict__ gamma,
                                             const float* __restrict__ beta,
                                             const float* __restrict__ mean,
                                             const float* __restrict__ var,
                                             float* __restrict__ Mp,
                                             float* __restrict__ shiftb) {
  int id = blockIdx.x * 256 + threadIdx.x;  // 0..131071
  int b = id >> 15;
  int rem = id & 32767;
  int co = rem >> 8;
  int c = rem & 255;
  int h = c >> 3, e = c & 7;
  float inv = gamma[co] * rsqrtf(var[co] + 1e-5f);
  const float* wrow = wproj + (size_t)co * 256 + h * 8;
  const float* vkc = vk + ((size_t)b * 32 + h) * 72 + e;
  float s = 0.f;
  #pragma unroll
  for (int d = 0; d < 8; ++d) s += wrow[d] * vkc[d * 8];
  Mp[id] = inv * s;
  if (b == 0 && c == 0) shiftb[co] = beta[co] - mean[co] * inv;
}

// ============================================================================
// K4: out[b,co,n] = sum_c M'[b,co,c] * Q'[c,n] + shift[co]
// Q'[8h+e][n] = relu(q)/den computed on the fly per 32-row chunk (4 heads).
// ============================================================================
__global__ __launch_bounds__(256) void k4_proj(const float* __restrict__ qkv,
                                               const float* __restrict__ agg,
                                               const float* __restrict__ vk,
                                               const float* __restrict__ Mp,
                                               const float* __restrict__ shiftb,
                                               float* __restrict__ out) {
  __shared__ __align__(16) float As[32 * 128];  // [k][co]
  __shared__ __align__(16) float Bs[32 * 128];  // [k][n] = Q'
  const int t = threadIdx.x;
  const int n0 = blockIdx.x * 128;
  const int b = blockIdx.y;
  float acc[8][8];
  #pragma unroll
  for (int i = 0; i < 8; ++i)
    #pragma unroll
    for (int j = 0; j < 8; ++j) acc[i][j] = 0.f;
  const int co_g = t >> 4;
  const int n_g = t & 15;

  for (int cidx = 0; cidx < 8; ++cidx) {
    const int c0 = cidx * 32;
    const int h0 = cidx * 4;
    {  // stage Q raw (relu) into Bs
      const int c_l = t >> 3;   // 0..31
      const int nq = t & 7;
      const int h = h0 + (c_l >> 3);
      const int e = c_l & 7;
      const float* srcb = (h < 16 ? qkv : agg);
      const float* src = srcb + ((size_t)b * T3 + (h & 15) * 24 + e) * NPIX + n0 + nq * 16;
      float4 v0 = ((const float4*)src)[0];
      float4 v1 = ((const float4*)src)[1];
      float4 v2 = ((const float4*)src)[2];
      float4 v3 = ((const float4*)src)[3];
      v0.x = fmaxf(v0.x, 0.f); v0.y = fmaxf(v0.y, 0.f); v0.z = fmaxf(v0.z, 0.f); v0.w = fmaxf(v0.w, 0.f);
      v1.x = fmaxf(v1.x, 0.f); v1.y = fmaxf(v1.y, 0.f); v1.z = fmaxf(v1.z, 0.f); v1.w = fmaxf(v1.w, 0.f);
      v2.x = fmaxf(v2.x, 0.f); v2.y = fmaxf(v2.y, 0.f); v2.z = fmaxf(v2.z, 0.f); v2.w = fmaxf(v2.w, 0.f);
      v3.x = fmaxf(v3.x, 0.f); v3.y = fmaxf(v3.y, 0.f); v3.z = fmaxf(v3.z, 0.f); v3.w = fmaxf(v3.w, 0.f);
      float* brow = &Bs[c_l * 128 + nq * 16];
      ((float4*)brow)[0] = v0;
      ((float4*)brow)[1] = v1;
      ((float4*)brow)[2] = v2;
      ((float4*)brow)[3] = v3;
    }
    {  // stage M' chunk transposed into As
      const int co_l = t >> 1;  // 0..127
      const int kq = t & 1;
      const float* mrow = Mp + ((size_t)b * 128 + co_l) * 256 + c0 + kq * 16;
      #pragma unroll
      for (int r = 0; r < 4; ++r) {
        float4 v = ((const float4*)mrow)[r];
        int k = kq * 16 + r * 4;
        As[(k + 0) * 128 + co_l] = v.x;
        As[(k + 1) * 128 + co_l] = v.y;
        As[(k + 2) * 128 + co_l] = v.z;
        As[(k + 3) * 128 + co_l] = v.w;
      }
    }
    __syncthreads();
    // den + rescale (each (hj,px) owns its 8 Bs entries -> no races)
    #pragma unroll
    for (int ss = 0; ss < 2; ++ss) {
      int s = t + ss * 256;      // 0..511
      int hj = s >> 7;           // 0..3
      int px = s & 127;
      const float* vkrow = vk + ((size_t)(b * 32) + h0 + hj) * 72 + 64;
      float q8[8];
      float den = 1e-15f;
      #pragma unroll
      for (int e = 0; e < 8; ++e) {
        q8[e] = Bs[(hj * 8 + e) * 128 + px];
        den += vkrow[e] * q8[e];
      }
      float r = 1.0f / den;
      #pragma unroll
      for (int e = 0; e < 8; ++e) Bs[(hj * 8 + e) * 128 + px] = q8[e] * r;
    }
    __syncthreads();
    #pragma unroll
    for (int kk = 0; kk < 32; ++kk) {
      float4 a0 = *(const float4*)&As[kk * 128 + co_g * 8];
      float4 a1 = *(const float4*)&As[kk * 128 + co_g * 8 + 4];
      float4 b0 = *(const float4*)&Bs[kk * 128 + n_g * 8];
      float4 b1 = *(const float4*)&Bs[kk * 128 + n_g * 8 + 4];
      float av[8] = {a0.x, a0.y, a0.z, a0.w, a1.x, a1.y, a1.z, a1.w};
      float bv[8] = {b0.x, b0.y, b0.z, b0.w, b1.x, b1.y, b1.z, b1.w};
      #pragma unroll
      for (int i = 0; i < 8; ++i)
        #pragma unroll
        for (int j = 0; j < 8; ++j) acc[i][j] += av[i] * bv[j];
    }
    __syncthreads();
  }
  #pragma unroll
  for (int i = 0; i < 8; ++i) {
    int co = co_g * 8 + i;
    float sh = shiftb[co];
    float* orow = out + ((size_t)b * 128 + co) * NPIX + n0 + n_g * 8;
    float4 o0 = make_float4(acc[i][0] + sh, acc[i][1] + sh, acc[i][2] + sh, acc[i][3] + sh);
    float4 o1 = make_float4(acc[i][4] + sh, acc[i][5] + sh, acc[i][6] + sh, acc[i][7] + sh);
    ((float4*)orow)[0] = o0;
    ((float4*)orow)[1] = o1;
  }
}

__global__ void fill_sentinel(float* o, int n) {
  int i = blockIdx.x * 256 + threadIdx.x;
  if (i < n) o[i] = 12345.0f;
}

extern "C" void kernel_launch(void* const* d_in, const int* in_sizes, int n_in,
                              void* d_out, int out_size, void* d_ws, size_t ws_size,
                              hipStream_t stream) {
  const float* x     = (const float*)d_in[0];
  const float* wqkv  = (const float*)d_in[1];
  const float* wdw   = (const float*)d_in[2];
  const float* wpw   = (const float*)d_in[3];
  const float* wproj = (const float*)d_in[4];
  const float* gamma = (const float*)d_in[5];
  const float* beta  = (const float*)d_in[6];
  const float* mean  = (const float*)d_in[7];
  const float* var   = (const float*)d_in[8];
  float* out = (float*)d_out;
  float* ws = (float*)d_ws;

  const size_t needF = (size_t)QKV_ELE * 2 + 36864 + 9216 + 131072 + 128;
  if (ws_size < needF * 4) {
    // unambiguous signal that ws is too small
    fill_sentinel<<<dim3((out_size + 255) / 256), dim3(256), 0, stream>>>(out, out_size);
    return;
  }
  float* qkv   = ws;
  float* agg   = qkv + QKV_ELE;
  float* part  = agg + QKV_ELE;      // 128*4*72
  float* vkbuf = part + 36864;       // 128*72
  float* Mp    = vkbuf + 9216;       // 4*128*256
  float* shiftb = Mp + 131072;       // 128

  k1_qkv<<<dim3(128, 3, 4), 256, 0, stream>>>(x, wqkv, qkv);
  k2_dwpw<<<dim3(4, 8, 192), 256, 0, stream>>>(qkv, wdw, wpw, agg);
  k3_vk<<<dim3(4, 128), 256, 0, stream>>>(qkv, agg, part);
  k3b_sum<<<dim3(128), 128, 0, stream>>>(part, vkbuf);
  k3c_M<<<dim3(512), 256, 0, stream>>>(wproj, vkbuf, gamma, beta, mean, var, Mp, shiftb);
  k4_proj<<<dim3(128, 4), 256, 0, stream>>>(qkv, agg, vkbuf, Mp, shiftb, out);
}

// Round 2
// 236.443 us; speedup vs baseline: 1.1728x; 1.1728x over previous
//
#include <hip/hip_runtime.h>

#define BB 4
#define CIN 128
#define T3 384
#define HH 128
#define WW 128
#define NPIX 16384
#define QKV_ELE (BB*T3*NPIX)   // 25165824 floats per big buffer
#define NCHUNK 16

// ============================================================================
// K1: qkv[b,co,n] = sum_ci wqkv[co,ci] * x[b,ci,n]   (GEMM 384x128 @ 128x16384)
// Tile: 128co x 128n, K-chunks of 32. 8x8 acc per thread (split frags: 2-way
// banks). Flat grid with XCD-grouping so the 3 co-tiles of one (n,b) tile
// share an XCD's L2 (x fetched from HBM once).
// ============================================================================
__global__ __launch_bounds__(256) void k1_qkv(const float* __restrict__ x,
                                              const float* __restrict__ wqkv,
                                              float* __restrict__ qkv) {
  __shared__ __align__(16) float As[32 * 128];  // [k][co]
  __shared__ __align__(16) float Bs[32 * 128];  // [k][n]
  const int t = threadIdx.x;
  // XCD-grouping: physical p -> (triple tt, member m); members 8 apart -> same XCD (p%8)
  const int p = blockIdx.x;            // 0..1535
  const int qd = p / 24;
  const int r = p - qd * 24;
  const int m = r >> 3;                // 0..2  -> co tile
  const int c8 = r & 7;
  const int tt = qd * 8 + c8;          // 0..511 -> (n_tile, b)
  const int n0 = (tt & 127) * 128;
  const int b = tt >> 7;
  const int co0 = m * 128;
  const float* xb = x + (size_t)b * CIN * NPIX;

  float acc[8][8];
  #pragma unroll
  for (int i = 0; i < 8; ++i)
    #pragma unroll
    for (int j = 0; j < 8; ++j) acc[i][j] = 0.f;

  const int co_g = t >> 4;   // 0..15
  const int n_g = t & 15;    // 0..15

  for (int k0 = 0; k0 < CIN; k0 += 32) {
    {  // stage A transposed: As[k][co]
      const int co_l = t >> 1;       // 0..127
      const int kq = t & 1;          // 0..1
      const float* mrow = wqkv + (size_t)(co0 + co_l) * CIN + k0 + kq * 16;
      #pragma unroll
      for (int rr = 0; rr < 4; ++rr) {
        float4 v = ((const float4*)mrow)[rr];
        int k = kq * 16 + rr * 4;
        As[(k + 0) * 128 + co_l] = v.x;
        As[(k + 1) * 128 + co_l] = v.y;
        As[(k + 2) * 128 + co_l] = v.z;
        As[(k + 3) * 128 + co_l] = v.w;
      }
    }
    {  // stage B: Bs[k][n]
      const int k_l = t >> 3;        // 0..31
      const int nq = t & 7;          // 0..7
      const float* xrow = xb + (size_t)(k0 + k_l) * NPIX + n0 + nq * 16;
      float4 v0 = ((const float4*)xrow)[0];
      float4 v1 = ((const float4*)xrow)[1];
      float4 v2 = ((const float4*)xrow)[2];
      float4 v3 = ((const float4*)xrow)[3];
      float* brow = &Bs[k_l * 128 + nq * 16];
      ((float4*)brow)[0] = v0;
      ((float4*)brow)[1] = v1;
      ((float4*)brow)[2] = v2;
      ((float4*)brow)[3] = v3;
    }
    __syncthreads();
    #pragma unroll
    for (int kk = 0; kk < 32; ++kk) {
      // split frags: {co_g*4 .. +3} and {64+co_g*4 .. +3} -> 16B stride, 2-way banks
      float4 a0 = *(const float4*)&As[kk * 128 + co_g * 4];
      float4 a1 = *(const float4*)&As[kk * 128 + 64 + co_g * 4];
      float4 b0 = *(const float4*)&Bs[kk * 128 + n_g * 4];
      float4 b1 = *(const float4*)&Bs[kk * 128 + 64 + n_g * 4];
      float av[8] = {a0.x, a0.y, a0.z, a0.w, a1.x, a1.y, a1.z, a1.w};
      float bv[8] = {b0.x, b0.y, b0.z, b0.w, b1.x, b1.y, b1.z, b1.w};
      #pragma unroll
      for (int i = 0; i < 8; ++i)
        #pragma unroll
        for (int j = 0; j < 8; ++j) acc[i][j] += av[i] * bv[j];
    }
    __syncthreads();
  }
  float* ob = qkv + (size_t)b * T3 * NPIX;
  #pragma unroll
  for (int i = 0; i < 8; ++i) {
    int co = co0 + ((i < 4) ? (co_g * 4 + i) : (64 + co_g * 4 + i - 4));
    float* orow = ob + (size_t)co * NPIX + n0;
    float4 o0 = make_float4(acc[i][0], acc[i][1], acc[i][2], acc[i][3]);
    float4 o1 = make_float4(acc[i][4], acc[i][5], acc[i][6], acc[i][7]);
    *(float4*)&orow[n_g * 4] = o0;
    *(float4*)&orow[64 + n_g * 4] = o1;
  }
}

// ============================================================================
// K2: agg = grouped_pw( dw5x5(qkv) ).  One block = (b, pw-group g of 8 ch,
// 32x16 pixel tile). ins pitch 40 (aligned float4, 2-way banks); dw-output
// staging reuses the ins buffer (union) -> 26.7 KB LDS -> 6 blocks/CU.
// ============================================================================
#define PIN 40   // ins row pitch (floats)
#define PDW 36   // dws row pitch (floats)
__global__ __launch_bounds__(256) void k2_dwpw(const float* __restrict__ qkv,
                                               const float* __restrict__ wdw,
                                               const float* __restrict__ wpw,
                                               float* __restrict__ agg) {
  __shared__ __align__(16) float smem[8 * 20 * PIN];  // 6400 floats; reused as dws[8*16*PDW]
  __shared__ float wds[8][25];
  __shared__ float wps[64];
  const int t = threadIdx.x;
  const int x0 = blockIdx.x * 32;
  const int y0 = blockIdx.y * 16;
  const int bg = blockIdx.z;       // 0..191
  const int b = bg / 48;
  const int g = bg % 48;
  const float* src = qkv + ((size_t)b * T3 + g * 8) * NPIX;

  // stage ins: 8ch x 20 rows x 36 cols as 1440 float4 slots
  for (int id = t; id < 1440; id += 256) {
    int ch = id / 180;
    int rem = id - ch * 180;
    int ry = rem / 9;
    int rx4 = (rem - ry * 9) * 4;      // 0..32
    int gy = y0 + ry - 2;
    int gx = x0 + rx4 - 2;
    float4 v = make_float4(0.f, 0.f, 0.f, 0.f);
    if ((unsigned)gy < (unsigned)HH) {
      const float* rp = src + (size_t)ch * NPIX + gy * WW + gx;
      if (gx >= 0 && gx + 3 < WW) {
        v = *(const float4*)rp;
      } else {
        if ((unsigned)gx < (unsigned)WW) v.x = rp[0];
        if ((unsigned)(gx + 1) < (unsigned)WW) v.y = rp[1];
        if ((unsigned)(gx + 2) < (unsigned)WW) v.z = rp[2];
        if ((unsigned)(gx + 3) < (unsigned)WW) v.w = rp[3];
      }
    }
    *(float4*)&smem[ch * (20 * PIN) + ry * PIN + rx4] = v;
  }
  for (int idx = t; idx < 200; idx += 256)
    wds[idx / 25][idx % 25] = wdw[(size_t)g * 200 + idx];
  if (t < 64) wps[t] = wpw[g * 64 + t];
  __syncthreads();

  // depthwise 5x5: thread -> (ch, 4x-cols, 4y-rows); pull 8x8 window to regs
  const int ch = t >> 5;          // 0..7
  const int xq = t & 7;           // 0..7
  const int yg = (t >> 3) & 3;    // 0..3
  float rbw[8][8];
  {
    const float* base = &smem[ch * (20 * PIN) + (yg * 4) * PIN + xq * 4];
    #pragma unroll
    for (int rr = 0; rr < 8; ++rr) {
      float4 u0 = *(const float4*)(base + rr * PIN);
      float4 u1 = *(const float4*)(base + rr * PIN + 4);
      rbw[rr][0] = u0.x; rbw[rr][1] = u0.y; rbw[rr][2] = u0.z; rbw[rr][3] = u0.w;
      rbw[rr][4] = u1.x; rbw[rr][5] = u1.y; rbw[rr][6] = u1.z; rbw[rr][7] = u1.w;
    }
  }
  float dacc[4][4];
  #pragma unroll
  for (int jy = 0; jy < 4; ++jy)
    #pragma unroll
    for (int jx = 0; jx < 4; ++jx) dacc[jy][jx] = 0.f;
  #pragma unroll
  for (int ky = 0; ky < 5; ++ky)
    #pragma unroll
    for (int kx = 0; kx < 5; ++kx) {
      float wv = wds[ch][ky * 5 + kx];
      #pragma unroll
      for (int jy = 0; jy < 4; ++jy)
        #pragma unroll
        for (int jx = 0; jx < 4; ++jx)
          dacc[jy][jx] += wv * rbw[jy + ky][jx + kx];
    }
  __syncthreads();   // all ins reads done -> safe to overwrite smem with dw output

  #pragma unroll
  for (int jy = 0; jy < 4; ++jy) {
    float4 o = make_float4(dacc[jy][0], dacc[jy][1], dacc[jy][2], dacc[jy][3]);
    *(float4*)&smem[ch * (16 * PDW) + (yg * 4 + jy) * PDW + xq * 4] = o;
  }
  __syncthreads();

  // grouped pointwise 8x8
  float* dst = agg + ((size_t)b * T3 + g * 8) * NPIX + (size_t)y0 * WW + x0;
  #pragma unroll
  for (int pp = 0; pp < 2; ++pp) {
    int pix = t + pp * 256;      // 0..511
    int py = pix >> 5;
    int px = pix & 31;
    float dv[8];
    #pragma unroll
    for (int ic = 0; ic < 8; ++ic) dv[ic] = smem[ic * (16 * PDW) + py * PDW + px];
    #pragma unroll
    for (int oc = 0; oc < 8; ++oc) {
      float s = 0.f;
      #pragma unroll
      for (int ic = 0; ic < 8; ++ic) s += wps[oc * 8 + ic] * dv[ic];
      dst[(size_t)oc * NPIX + py * WW + px] = s;
    }
  }
}

// ============================================================================
// K3: vk partials. block=(chunk, bh); 4 waves: wave w owns d rows {2w,2w+1},
// wave 0 also d=8 (k-colsum). Deterministic; k3b sums the NCHUNK chunks.
// ============================================================================
__global__ __launch_bounds__(256) void k3_vk(const float* __restrict__ qkv,
                                             const float* __restrict__ agg,
                                             float* __restrict__ part) {
  const int chunk = blockIdx.x;  // 0..NCHUNK-1
  const int bh = blockIdx.y;     // 0..127
  const int b = bh >> 5;
  const int h = bh & 31;
  const int hh = h & 15;
  const float* base = (h < 16 ? qkv : agg) + ((size_t)b * T3 + hh * 24) * NPIX;
  const float* kb = base + 8 * NPIX;
  const float* vb = base + 16 * NPIX;
  const int t = threadIdx.x;
  const int wv = t >> 6;
  const int lane = t & 63;
  const int d0 = wv * 2;

  float accA[8], accB[8], accS[8];
  #pragma unroll
  for (int e = 0; e < 8; ++e) { accA[e] = 0.f; accB[e] = 0.f; accS[e] = 0.f; }

  int p = chunk * (NPIX / NCHUNK) + lane;
  for (int it = 0; it < (NPIX / NCHUNK / 64); ++it, p += 64) {
    float kvv[8];
    #pragma unroll
    for (int e = 0; e < 8; ++e) kvv[e] = fmaxf(kb[(size_t)e * NPIX + p], 0.f);
    float vA = vb[(size_t)d0 * NPIX + p];
    float vB = vb[(size_t)(d0 + 1) * NPIX + p];
    #pragma unroll
    for (int e = 0; e < 8; ++e) { accA[e] += vA * kvv[e]; accB[e] += vB * kvv[e]; }
    if (wv == 0) {
      #pragma unroll
      for (int e = 0; e < 8; ++e) accS[e] += kvv[e];
    }
  }
  #pragma unroll
  for (int e = 0; e < 8; ++e) {
    #pragma unroll
    for (int m = 1; m < 64; m <<= 1) {
      accA[e] += __shfl_xor(accA[e], m);
      accB[e] += __shfl_xor(accB[e], m);
    }
  }
  if (wv == 0) {
    #pragma unroll
    for (int e = 0; e < 8; ++e)
      #pragma unroll
      for (int m = 1; m < 64; m <<= 1) accS[e] += __shfl_xor(accS[e], m);
  }
  if (lane == 0) {
    float* pr = part + ((size_t)bh * NCHUNK + chunk) * 72;
    #pragma unroll
    for (int e = 0; e < 8; ++e) {
      pr[d0 * 8 + e] = accA[e];
      pr[(d0 + 1) * 8 + e] = accB[e];
    }
    if (wv == 0) {
      #pragma unroll
      for (int e = 0; e < 8; ++e) pr[64 + e] = accS[e];
    }
  }
}

__global__ __launch_bounds__(128) void k3b_sum(const float* __restrict__ part,
                                               float* __restrict__ vk) {
  const int bh = blockIdx.x;
  const int j = threadIdx.x;
  if (j < 72) {
    float s = 0.f;
    #pragma unroll
    for (int c = 0; c < NCHUNK; ++c) s += part[((size_t)bh * NCHUNK + c) * 72 + j];
    vk[(size_t)bh * 72 + j] = s;
  }
}

// ============================================================================
// K3c: M'[b][co][8h+e] = inv[co] * sum_d Wp[co][8h+d] * vk[b,h,d,e];
//      shift[co] = beta - mean*inv   (BN folded)
// ============================================================================
__global__ __launch_bounds__(256) void k3c_M(const float* __restrict__ wproj,
                                             const float* __restrict__ vk,
                                             const float* __restrict__ gamma,
                                             const float* __restrict__ beta,
                                             const float* __restrict__ mean,
                                             const float* __restrict__ var,
                                             float* __restrict__ Mp,
                                             float* __restrict__ shiftb) {
  int id = blockIdx.x * 256 + threadIdx.x;  // 0..131071
  int b = id >> 15;
  int rem = id & 32767;
  int co = rem >> 8;
  int c = rem & 255;
  int h = c >> 3, e = c & 7;
  float inv = gamma[co] * rsqrtf(var[co] + 1e-5f);
  const float* wrow = wproj + (size_t)co * 256 + h * 8;
  const float* vkc = vk + ((size_t)b * 32 + h) * 72 + e;
  float s = 0.f;
  #pragma unroll
  for (int d = 0; d < 8; ++d) s += wrow[d] * vkc[d * 8];
  Mp[id] = inv * s;
  if (b == 0 && c == 0) shiftb[co] = beta[co] - mean[co] * inv;
}

// ============================================================================
// K4: out[b,co,n] = sum_c M'[b,co,c] * Q'[c,n] + shift[co]
// Q'[8h+e][n] = relu(q)/den computed on the fly per 32-row chunk (4 heads).
// Split frags for 2-way LDS banks.
// ============================================================================
__global__ __launch_bounds__(256) void k4_proj(const float* __restrict__ qkv,
                                               const float* __restrict__ agg,
                                               const float* __restrict__ vk,
                                               const float* __restrict__ Mp,
                                               const float* __restrict__ shiftb,
                                               float* __restrict__ out) {
  __shared__ __align__(16) float As[32 * 128];  // [k][co]
  __shared__ __align__(16) float Bs[32 * 128];  // [k][n] = Q'
  const int t = threadIdx.x;
  const int n0 = blockIdx.x * 128;
  const int b = blockIdx.y;
  float acc[8][8];
  #pragma unroll
  for (int i = 0; i < 8; ++i)
    #pragma unroll
    for (int j = 0; j < 8; ++j) acc[i][j] = 0.f;
  const int co_g = t >> 4;
  const int n_g = t & 15;

  for (int cidx = 0; cidx < 8; ++cidx) {
    const int c0 = cidx * 32;
    const int h0 = cidx * 4;
    {  // stage Q raw (relu) into Bs
      const int c_l = t >> 3;   // 0..31
      const int nq = t & 7;
      const int h = h0 + (c_l >> 3);
      const int e = c_l & 7;
      const float* srcb = (h < 16 ? qkv : agg);
      const float* src = srcb + ((size_t)b * T3 + (h & 15) * 24 + e) * NPIX + n0 + nq * 16;
      float4 v0 = ((const float4*)src)[0];
      float4 v1 = ((const float4*)src)[1];
      float4 v2 = ((const float4*)src)[2];
      float4 v3 = ((const float4*)src)[3];
      v0.x = fmaxf(v0.x, 0.f); v0.y = fmaxf(v0.y, 0.f); v0.z = fmaxf(v0.z, 0.f); v0.w = fmaxf(v0.w, 0.f);
      v1.x = fmaxf(v1.x, 0.f); v1.y = fmaxf(v1.y, 0.f); v1.z = fmaxf(v1.z, 0.f); v1.w = fmaxf(v1.w, 0.f);
      v2.x = fmaxf(v2.x, 0.f); v2.y = fmaxf(v2.y, 0.f); v2.z = fmaxf(v2.z, 0.f); v2.w = fmaxf(v2.w, 0.f);
      v3.x = fmaxf(v3.x, 0.f); v3.y = fmaxf(v3.y, 0.f); v3.z = fmaxf(v3.z, 0.f); v3.w = fmaxf(v3.w, 0.f);
      float* brow = &Bs[c_l * 128 + nq * 16];
      ((float4*)brow)[0] = v0;
      ((float4*)brow)[1] = v1;
      ((float4*)brow)[2] = v2;
      ((float4*)brow)[3] = v3;
    }
    {  // stage M' chunk transposed into As
      const int co_l = t >> 1;  // 0..127
      const int kq = t & 1;
      const float* mrow = Mp + ((size_t)b * 128 + co_l) * 256 + c0 + kq * 16;
      #pragma unroll
      for (int rr = 0; rr < 4; ++rr) {
        float4 v = ((const float4*)mrow)[rr];
        int k = kq * 16 + rr * 4;
        As[(k + 0) * 128 + co_l] = v.x;
        As[(k + 1) * 128 + co_l] = v.y;
        As[(k + 2) * 128 + co_l] = v.z;
        As[(k + 3) * 128 + co_l] = v.w;
      }
    }
    __syncthreads();
    // den + rescale (each (hj,px) owns its 8 Bs entries -> no races)
    #pragma unroll
    for (int ss = 0; ss < 2; ++ss) {
      int s = t + ss * 256;      // 0..511
      int hj = s >> 7;           // 0..3
      int px = s & 127;
      const float* vkrow = vk + ((size_t)(b * 32) + h0 + hj) * 72 + 64;
      float q8[8];
      float den = 1e-15f;
      #pragma unroll
      for (int e = 0; e < 8; ++e) {
        q8[e] = Bs[(hj * 8 + e) * 128 + px];
        den += vkrow[e] * q8[e];
      }
      float rden = 1.0f / den;
      #pragma unroll
      for (int e = 0; e < 8; ++e) Bs[(hj * 8 + e) * 128 + px] = q8[e] * rden;
    }
    __syncthreads();
    #pragma unroll
    for (int kk = 0; kk < 32; ++kk) {
      float4 a0 = *(const float4*)&As[kk * 128 + co_g * 4];
      float4 a1 = *(const float4*)&As[kk * 128 + 64 + co_g * 4];
      float4 b0 = *(const float4*)&Bs[kk * 128 + n_g * 4];
      float4 b1 = *(const float4*)&Bs[kk * 128 + 64 + n_g * 4];
      float av[8] = {a0.x, a0.y, a0.z, a0.w, a1.x, a1.y, a1.z, a1.w};
      float bv[8] = {b0.x, b0.y, b0.z, b0.w, b1.x, b1.y, b1.z, b1.w};
      #pragma unroll
      for (int i = 0; i < 8; ++i)
        #pragma unroll
        for (int j = 0; j < 8; ++j) acc[i][j] += av[i] * bv[j];
    }
    __syncthreads();
  }
  #pragma unroll
  for (int i = 0; i < 8; ++i) {
    int co = (i < 4) ? (co_g * 4 + i) : (64 + co_g * 4 + i - 4);
    float sh = shiftb[co];
    float* orow = out + ((size_t)b * 128 + co) * NPIX + n0;
    float4 o0 = make_float4(acc[i][0] + sh, acc[i][1] + sh, acc[i][2] + sh, acc[i][3] + sh);
    float4 o1 = make_float4(acc[i][4] + sh, acc[i][5] + sh, acc[i][6] + sh, acc[i][7] + sh);
    *(float4*)&orow[n_g * 4] = o0;
    *(float4*)&orow[64 + n_g * 4] = o1;
  }
}

__global__ void fill_sentinel(float* o, int n) {
  int i = blockIdx.x * 256 + threadIdx.x;
  if (i < n) o[i] = 12345.0f;
}

extern "C" void kernel_launch(void* const* d_in, const int* in_sizes, int n_in,
                              void* d_out, int out_size, void* d_ws, size_t ws_size,
                              hipStream_t stream) {
  const float* x     = (const float*)d_in[0];
  const float* wqkv  = (const float*)d_in[1];
  const float* wdw   = (const float*)d_in[2];
  const float* wpw   = (const float*)d_in[3];
  const float* wproj = (const float*)d_in[4];
  const float* gamma = (const float*)d_in[5];
  const float* beta  = (const float*)d_in[6];
  const float* mean  = (const float*)d_in[7];
  const float* var   = (const float*)d_in[8];
  float* out = (float*)d_out;
  float* ws = (float*)d_ws;

  const size_t partF = 128 * NCHUNK * 72;
  const size_t needF = (size_t)QKV_ELE * 2 + partF + 9216 + 131072 + 128;
  if (ws_size < needF * 4) {
    fill_sentinel<<<dim3((out_size + 255) / 256), dim3(256), 0, stream>>>(out, out_size);
    return;
  }
  float* qkv    = ws;
  float* agg    = qkv + QKV_ELE;
  float* part   = agg + QKV_ELE;
  float* vkbuf  = part + partF;       // 128*72
  float* Mp     = vkbuf + 9216;       // 4*128*256
  float* shiftb = Mp + 131072;        // 128

  k1_qkv<<<dim3(1536), 256, 0, stream>>>(x, wqkv, qkv);
  k2_dwpw<<<dim3(4, 8, 192), 256, 0, stream>>>(qkv, wdw, wpw, agg);
  k3_vk<<<dim3(NCHUNK, 128), 256, 0, stream>>>(qkv, agg, part);
  k3b_sum<<<dim3(128), 128, 0, stream>>>(part, vkbuf);
  k3c_M<<<dim3(512), 256, 0, stream>>>(wproj, vkbuf, gamma, beta, mean, var, Mp, shiftb);
  k4_proj<<<dim3(128, 4), 256, 0, stream>>>(qkv, agg, vkbuf, Mp, shiftb, out);
}

// Round 3
// 236.280 us; speedup vs baseline: 1.1736x; 1.0007x over previous
//
#include <hip/hip_runtime.h>

#define BB 4
#define CIN 128
#define T3 384
#define HH 128
#define WW 128
#define NPIX 16384
#define QKV_ELE (BB*T3*NPIX)   // 25165824 floats per big buffer
#define NCHUNK 16
#define PB 132   // padded Bs pitch: 132*4B = 528B ≡ 16 (mod 128B) -> staging writes hit all 32 banks

// ============================================================================
// K1: qkv[b,co,n] = sum_ci wqkv[co,ci] * x[b,ci,n]   (GEMM 384x128 @ 128x16384)
// Tile: 128co x 128n, K-chunks of 32. 8x8 acc per thread (split frags: 2-way
// banks). Flat grid with XCD-grouping so the 3 co-tiles of one (n,b) tile
// share an XCD's L2 (x fetched from HBM once). Bs padded to PB=132.
// ============================================================================
__global__ __launch_bounds__(256) void k1_qkv(const float* __restrict__ x,
                                              const float* __restrict__ wqkv,
                                              float* __restrict__ qkv) {
  __shared__ __align__(16) float As[32 * 128];  // [k][co]
  __shared__ __align__(16) float Bs[32 * PB];   // [k][n], padded
  const int t = threadIdx.x;
  // XCD-grouping: physical p -> (triple tt, member m); members 8 apart -> same XCD (p%8)
  const int p = blockIdx.x;            // 0..1535
  const int qd = p / 24;
  const int r = p - qd * 24;
  const int m = r >> 3;                // 0..2  -> co tile
  const int c8 = r & 7;
  const int tt = qd * 8 + c8;          // 0..511 -> (n_tile, b)
  const int n0 = (tt & 127) * 128;
  const int b = tt >> 7;
  const int co0 = m * 128;
  const float* xb = x + (size_t)b * CIN * NPIX;

  float acc[8][8];
  #pragma unroll
  for (int i = 0; i < 8; ++i)
    #pragma unroll
    for (int j = 0; j < 8; ++j) acc[i][j] = 0.f;

  const int co_g = t >> 4;   // 0..15
  const int n_g = t & 15;    // 0..15

  for (int k0 = 0; k0 < CIN; k0 += 32) {
    {  // stage A transposed: As[k][co]
      const int co_l = t >> 1;       // 0..127
      const int kq = t & 1;          // 0..1
      const float* mrow = wqkv + (size_t)(co0 + co_l) * CIN + k0 + kq * 16;
      #pragma unroll
      for (int rr = 0; rr < 4; ++rr) {
        float4 v = ((const float4*)mrow)[rr];
        int k = kq * 16 + rr * 4;
        As[(k + 0) * 128 + co_l] = v.x;
        As[(k + 1) * 128 + co_l] = v.y;
        As[(k + 2) * 128 + co_l] = v.z;
        As[(k + 3) * 128 + co_l] = v.w;
      }
    }
    {  // stage B: Bs[k][n] (padded pitch)
      const int k_l = t >> 3;        // 0..31
      const int nq = t & 7;          // 0..7
      const float* xrow = xb + (size_t)(k0 + k_l) * NPIX + n0 + nq * 16;
      float4 v0 = ((const float4*)xrow)[0];
      float4 v1 = ((const float4*)xrow)[1];
      float4 v2 = ((const float4*)xrow)[2];
      float4 v3 = ((const float4*)xrow)[3];
      float* brow = &Bs[k_l * PB + nq * 16];
      ((float4*)brow)[0] = v0;
      ((float4*)brow)[1] = v1;
      ((float4*)brow)[2] = v2;
      ((float4*)brow)[3] = v3;
    }
    __syncthreads();
    #pragma unroll
    for (int kk = 0; kk < 32; ++kk) {
      // split frags: {co_g*4 .. +3} and {64+co_g*4 .. +3} -> 16B stride, 2-way banks
      float4 a0 = *(const float4*)&As[kk * 128 + co_g * 4];
      float4 a1 = *(const float4*)&As[kk * 128 + 64 + co_g * 4];
      float4 b0 = *(const float4*)&Bs[kk * PB + n_g * 4];
      float4 b1 = *(const float4*)&Bs[kk * PB + 64 + n_g * 4];
      float av[8] = {a0.x, a0.y, a0.z, a0.w, a1.x, a1.y, a1.z, a1.w};
      float bv[8] = {b0.x, b0.y, b0.z, b0.w, b1.x, b1.y, b1.z, b1.w};
      #pragma unroll
      for (int i = 0; i < 8; ++i)
        #pragma unroll
        for (int j = 0; j < 8; ++j) acc[i][j] += av[i] * bv[j];
    }
    __syncthreads();
  }
  float* ob = qkv + (size_t)b * T3 * NPIX;
  #pragma unroll
  for (int i = 0; i < 8; ++i) {
    int co = co0 + ((i < 4) ? (co_g * 4 + i) : (64 + co_g * 4 + i - 4));
    float* orow = ob + (size_t)co * NPIX + n0;
    float4 o0 = make_float4(acc[i][0], acc[i][1], acc[i][2], acc[i][3]);
    float4 o1 = make_float4(acc[i][4], acc[i][5], acc[i][6], acc[i][7]);
    *(float4*)&orow[n_g * 4] = o0;
    *(float4*)&orow[64 + n_g * 4] = o1;
  }
}

// ============================================================================
// K2: agg = grouped_pw( dw5x5(qkv) ).  One block = (b, pw-group g of 8 ch,
// 32x16 pixel tile). ins pitch 40 (aligned float4, 2-way banks); dw-output
// staging reuses the ins buffer (union) -> 26.7 KB LDS -> 6 blocks/CU.
// ============================================================================
#define PIN 40   // ins row pitch (floats)
#define PDW 36   // dws row pitch (floats)
__global__ __launch_bounds__(256) void k2_dwpw(const float* __restrict__ qkv,
                                               const float* __restrict__ wdw,
                                               const float* __restrict__ wpw,
                                               float* __restrict__ agg) {
  __shared__ __align__(16) float smem[8 * 20 * PIN];  // 6400 floats; reused as dws[8*16*PDW]
  __shared__ float wds[8][25];
  __shared__ float wps[64];
  const int t = threadIdx.x;
  const int x0 = blockIdx.x * 32;
  const int y0 = blockIdx.y * 16;
  const int bg = blockIdx.z;       // 0..191
  const int b = bg / 48;
  const int g = bg % 48;
  const float* src = qkv + ((size_t)b * T3 + g * 8) * NPIX;

  // stage ins: 8ch x 20 rows x 36 cols as 1440 float4 slots
  for (int id = t; id < 1440; id += 256) {
    int ch = id / 180;
    int rem = id - ch * 180;
    int ry = rem / 9;
    int rx4 = (rem - ry * 9) * 4;      // 0..32
    int gy = y0 + ry - 2;
    int gx = x0 + rx4 - 2;
    float4 v = make_float4(0.f, 0.f, 0.f, 0.f);
    if ((unsigned)gy < (unsigned)HH) {
      const float* rp = src + (size_t)ch * NPIX + gy * WW + gx;
      if (gx >= 0 && gx + 3 < WW) {
        v = *(const float4*)rp;
      } else {
        if ((unsigned)gx < (unsigned)WW) v.x = rp[0];
        if ((unsigned)(gx + 1) < (unsigned)WW) v.y = rp[1];
        if ((unsigned)(gx + 2) < (unsigned)WW) v.z = rp[2];
        if ((unsigned)(gx + 3) < (unsigned)WW) v.w = rp[3];
      }
    }
    *(float4*)&smem[ch * (20 * PIN) + ry * PIN + rx4] = v;
  }
  for (int idx = t; idx < 200; idx += 256)
    wds[idx / 25][idx % 25] = wdw[(size_t)g * 200 + idx];
  if (t < 64) wps[t] = wpw[g * 64 + t];
  __syncthreads();

  // depthwise 5x5: thread -> (ch, 4x-cols, 4y-rows); pull 8x8 window to regs
  const int ch = t >> 5;          // 0..7
  const int xq = t & 7;           // 0..7
  const int yg = (t >> 3) & 3;    // 0..3
  float rbw[8][8];
  {
    const float* base = &smem[ch * (20 * PIN) + (yg * 4) * PIN + xq * 4];
    #pragma unroll
    for (int rr = 0; rr < 8; ++rr) {
      float4 u0 = *(const float4*)(base + rr * PIN);
      float4 u1 = *(const float4*)(base + rr * PIN + 4);
      rbw[rr][0] = u0.x; rbw[rr][1] = u0.y; rbw[rr][2] = u0.z; rbw[rr][3] = u0.w;
      rbw[rr][4] = u1.x; rbw[rr][5] = u1.y; rbw[rr][6] = u1.z; rbw[rr][7] = u1.w;
    }
  }
  float dacc[4][4];
  #pragma unroll
  for (int jy = 0; jy < 4; ++jy)
    #pragma unroll
    for (int jx = 0; jx < 4; ++jx) dacc[jy][jx] = 0.f;
  #pragma unroll
  for (int ky = 0; ky < 5; ++ky)
    #pragma unroll
    for (int kx = 0; kx < 5; ++kx) {
      float wv = wds[ch][ky * 5 + kx];
      #pragma unroll
      for (int jy = 0; jy < 4; ++jy)
        #pragma unroll
        for (int jx = 0; jx < 4; ++jx)
          dacc[jy][jx] += wv * rbw[jy + ky][jx + kx];
    }
  __syncthreads();   // all ins reads done -> safe to overwrite smem with dw output

  #pragma unroll
  for (int jy = 0; jy < 4; ++jy) {
    float4 o = make_float4(dacc[jy][0], dacc[jy][1], dacc[jy][2], dacc[jy][3]);
    *(float4*)&smem[ch * (16 * PDW) + (yg * 4 + jy) * PDW + xq * 4] = o;
  }
  __syncthreads();

  // grouped pointwise 8x8
  float* dst = agg + ((size_t)b * T3 + g * 8) * NPIX + (size_t)y0 * WW + x0;
  #pragma unroll
  for (int pp = 0; pp < 2; ++pp) {
    int pix = t + pp * 256;      // 0..511
    int py = pix >> 5;
    int px = pix & 31;
    float dv[8];
    #pragma unroll
    for (int ic = 0; ic < 8; ++ic) dv[ic] = smem[ic * (16 * PDW) + py * PDW + px];
    #pragma unroll
    for (int oc = 0; oc < 8; ++oc) {
      float s = 0.f;
      #pragma unroll
      for (int ic = 0; ic < 8; ++ic) s += wps[oc * 8 + ic] * dv[ic];
      dst[(size_t)oc * NPIX + py * WW + px] = s;
    }
  }
}

// ============================================================================
// K3: vk partials. block=(chunk, bh); 4 waves: wave w owns d rows {2w,2w+1},
// wave 0 also d=8 (k-colsum). Deterministic; k3b sums the NCHUNK chunks.
// ============================================================================
__global__ __launch_bounds__(256) void k3_vk(const float* __restrict__ qkv,
                                             const float* __restrict__ agg,
                                             float* __restrict__ part) {
  const int chunk = blockIdx.x;  // 0..NCHUNK-1
  const int bh = blockIdx.y;     // 0..127
  const int b = bh >> 5;
  const int h = bh & 31;
  const int hh = h & 15;
  const float* base = (h < 16 ? qkv : agg) + ((size_t)b * T3 + hh * 24) * NPIX;
  const float* kb = base + 8 * NPIX;
  const float* vb = base + 16 * NPIX;
  const int t = threadIdx.x;
  const int wv = t >> 6;
  const int lane = t & 63;
  const int d0 = wv * 2;

  float accA[8], accB[8], accS[8];
  #pragma unroll
  for (int e = 0; e < 8; ++e) { accA[e] = 0.f; accB[e] = 0.f; accS[e] = 0.f; }

  int p = chunk * (NPIX / NCHUNK) + lane;
  for (int it = 0; it < (NPIX / NCHUNK / 64); ++it, p += 64) {
    float kvv[8];
    #pragma unroll
    for (int e = 0; e < 8; ++e) kvv[e] = fmaxf(kb[(size_t)e * NPIX + p], 0.f);
    float vA = vb[(size_t)d0 * NPIX + p];
    float vB = vb[(size_t)(d0 + 1) * NPIX + p];
    #pragma unroll
    for (int e = 0; e < 8; ++e) { accA[e] += vA * kvv[e]; accB[e] += vB * kvv[e]; }
    if (wv == 0) {
      #pragma unroll
      for (int e = 0; e < 8; ++e) accS[e] += kvv[e];
    }
  }
  #pragma unroll
  for (int e = 0; e < 8; ++e) {
    #pragma unroll
    for (int m = 1; m < 64; m <<= 1) {
      accA[e] += __shfl_xor(accA[e], m);
      accB[e] += __shfl_xor(accB[e], m);
    }
  }
  if (wv == 0) {
    #pragma unroll
    for (int e = 0; e < 8; ++e)
      #pragma unroll
      for (int m = 1; m < 64; m <<= 1) accS[e] += __shfl_xor(accS[e], m);
  }
  if (lane == 0) {
    float* pr = part + ((size_t)bh * NCHUNK + chunk) * 72;
    #pragma unroll
    for (int e = 0; e < 8; ++e) {
      pr[d0 * 8 + e] = accA[e];
      pr[(d0 + 1) * 8 + e] = accB[e];
    }
    if (wv == 0) {
      #pragma unroll
      for (int e = 0; e < 8; ++e) pr[64 + e] = accS[e];
    }
  }
}

__global__ __launch_bounds__(128) void k3b_sum(const float* __restrict__ part,
                                               float* __restrict__ vk) {
  const int bh = blockIdx.x;
  const int j = threadIdx.x;
  if (j < 72) {
    float s = 0.f;
    #pragma unroll
    for (int c = 0; c < NCHUNK; ++c) s += part[((size_t)bh * NCHUNK + c) * 72 + j];
    vk[(size_t)bh * 72 + j] = s;
  }
}

// ============================================================================
// K3c: M'[b][co][8h+e] = inv[co] * sum_d Wp[co][8h+d] * vk[b,h,d,e];
//      shift[co] = beta - mean*inv   (BN folded)
// ============================================================================
__global__ __launch_bounds__(256) void k3c_M(const float* __restrict__ wproj,
                                             const float* __restrict__ vk,
                                             const float* __restrict__ gamma,
                                             const float* __restrict__ beta,
                                             const float* __restrict__ mean,
                                             const float* __restrict__ var,
                                             float* __restrict__ Mp,
                                             float* __restrict__ shiftb) {
  int id = blockIdx.x * 256 + threadIdx.x;  // 0..131071
  int b = id >> 15;
  int rem = id & 32767;
  int co = rem >> 8;
  int c = rem & 255;
  int h = c >> 3, e = c & 7;
  float inv = gamma[co] * rsqrtf(var[co] + 1e-5f);
  const float* wrow = wproj + (size_t)co * 256 + h * 8;
  const float* vkc = vk + ((size_t)b * 32 + h) * 72 + e;
  float s = 0.f;
  #pragma unroll
  for (int d = 0; d < 8; ++d) s += wrow[d] * vkc[d * 8];
  Mp[id] = inv * s;
  if (b == 0 && c == 0) shiftb[co] = beta[co] - mean[co] * inv;
}

// ============================================================================
// K4: out[b,co,n] = sum_c M'[b,co,c] * Q'[c,n] + shift[co]
// Q'[8h+e][n] = relu(q)/den computed on the fly per 32-row chunk (4 heads).
// Split frags for 2-way LDS banks. Bs padded to PB=132.
// ============================================================================
__global__ __launch_bounds__(256) void k4_proj(const float* __restrict__ qkv,
                                               const float* __restrict__ agg,
                                               const float* __restrict__ vk,
                                               const float* __restrict__ Mp,
                                               const float* __restrict__ shiftb,
                                               float* __restrict__ out) {
  __shared__ __align__(16) float As[32 * 128];  // [k][co]
  __shared__ __align__(16) float Bs[32 * PB];   // [k][n] = Q', padded
  const int t = threadIdx.x;
  const int n0 = blockIdx.x * 128;
  const int b = blockIdx.y;
  float acc[8][8];
  #pragma unroll
  for (int i = 0; i < 8; ++i)
    #pragma unroll
    for (int j = 0; j < 8; ++j) acc[i][j] = 0.f;
  const int co_g = t >> 4;
  const int n_g = t & 15;

  for (int cidx = 0; cidx < 8; ++cidx) {
    const int c0 = cidx * 32;
    const int h0 = cidx * 4;
    {  // stage Q raw (relu) into Bs
      const int c_l = t >> 3;   // 0..31
      const int nq = t & 7;
      const int h = h0 + (c_l >> 3);
      const int e = c_l & 7;
      const float* srcb = (h < 16 ? qkv : agg);
      const float* src = srcb + ((size_t)b * T3 + (h & 15) * 24 + e) * NPIX + n0 + nq * 16;
      float4 v0 = ((const float4*)src)[0];
      float4 v1 = ((const float4*)src)[1];
      float4 v2 = ((const float4*)src)[2];
      float4 v3 = ((const float4*)src)[3];
      v0.x = fmaxf(v0.x, 0.f); v0.y = fmaxf(v0.y, 0.f); v0.z = fmaxf(v0.z, 0.f); v0.w = fmaxf(v0.w, 0.f);
      v1.x = fmaxf(v1.x, 0.f); v1.y = fmaxf(v1.y, 0.f); v1.z = fmaxf(v1.z, 0.f); v1.w = fmaxf(v1.w, 0.f);
      v2.x = fmaxf(v2.x, 0.f); v2.y = fmaxf(v2.y, 0.f); v2.z = fmaxf(v2.z, 0.f); v2.w = fmaxf(v2.w, 0.f);
      v3.x = fmaxf(v3.x, 0.f); v3.y = fmaxf(v3.y, 0.f); v3.z = fmaxf(v3.z, 0.f); v3.w = fmaxf(v3.w, 0.f);
      float* brow = &Bs[c_l * PB + nq * 16];
      ((float4*)brow)[0] = v0;
      ((float4*)brow)[1] = v1;
      ((float4*)brow)[2] = v2;
      ((float4*)brow)[3] = v3;
    }
    {  // stage M' chunk transposed into As
      const int co_l = t >> 1;  // 0..127
      const int kq = t & 1;
      const float* mrow = Mp + ((size_t)b * 128 + co_l) * 256 + c0 + kq * 16;
      #pragma unroll
      for (int rr = 0; rr < 4; ++rr) {
        float4 v = ((const float4*)mrow)[rr];
        int k = kq * 16 + rr * 4;
        As[(k + 0) * 128 + co_l] = v.x;
        As[(k + 1) * 128 + co_l] = v.y;
        As[(k + 2) * 128 + co_l] = v.z;
        As[(k + 3) * 128 + co_l] = v.w;
      }
    }
    __syncthreads();
    // den + rescale (each (hj,px) owns its 8 Bs entries -> no races)
    #pragma unroll
    for (int ss = 0; ss < 2; ++ss) {
      int s = t + ss * 256;      // 0..511
      int hj = s >> 7;           // 0..3
      int px = s & 127;
      const float* vkrow = vk + ((size_t)(b * 32) + h0 + hj) * 72 + 64;
      float q8[8];
      float den = 1e-15f;
      #pragma unroll
      for (int e = 0; e < 8; ++e) {
        q8[e] = Bs[(hj * 8 + e) * PB + px];
        den += vkrow[e] * q8[e];
      }
      float rden = 1.0f / den;
      #pragma unroll
      for (int e = 0; e < 8; ++e) Bs[(hj * 8 + e) * PB + px] = q8[e] * rden;
    }
    __syncthreads();
    #pragma unroll
    for (int kk = 0; kk < 32; ++kk) {
      float4 a0 = *(const float4*)&As[kk * 128 + co_g * 4];
      float4 a1 = *(const float4*)&As[kk * 128 + 64 + co_g * 4];
      float4 b0 = *(const float4*)&Bs[kk * PB + n_g * 4];
      float4 b1 = *(const float4*)&Bs[kk * PB + 64 + n_g * 4];
      float av[8] = {a0.x, a0.y, a0.z, a0.w, a1.x, a1.y, a1.z, a1.w};
      float bv[8] = {b0.x, b0.y, b0.z, b0.w, b1.x, b1.y, b1.z, b1.w};
      #pragma unroll
      for (int i = 0; i < 8; ++i)
        #pragma unroll
        for (int j = 0; j < 8; ++j) acc[i][j] += av[i] * bv[j];
    }
    __syncthreads();
  }
  #pragma unroll
  for (int i = 0; i < 8; ++i) {
    int co = (i < 4) ? (co_g * 4 + i) : (64 + co_g * 4 + i - 4);
    float sh = shiftb[co];
    float* orow = out + ((size_t)b * 128 + co) * NPIX + n0;
    float4 o0 = make_float4(acc[i][0] + sh, acc[i][1] + sh, acc[i][2] + sh, acc[i][3] + sh);
    float4 o1 = make_float4(acc[i][4] + sh, acc[i][5] + sh, acc[i][6] + sh, acc[i][7] + sh);
    *(float4*)&orow[n_g * 4] = o0;
    *(float4*)&orow[64 + n_g * 4] = o1;
  }
}

__global__ void fill_sentinel(float* o, int n) {
  int i = blockIdx.x * 256 + threadIdx.x;
  if (i < n) o[i] = 12345.0f;
}

extern "C" void kernel_launch(void* const* d_in, const int* in_sizes, int n_in,
                              void* d_out, int out_size, void* d_ws, size_t ws_size,
                              hipStream_t stream) {
  const float* x     = (const float*)d_in[0];
  const float* wqkv  = (const float*)d_in[1];
  const float* wdw   = (const float*)d_in[2];
  const float* wpw   = (const float*)d_in[3];
  const float* wproj = (const float*)d_in[4];
  const float* gamma = (const float*)d_in[5];
  const float* beta  = (const float*)d_in[6];
  const float* mean  = (const float*)d_in[7];
  const float* var   = (const float*)d_in[8];
  float* out = (float*)d_out;
  float* ws = (float*)d_ws;

  const size_t partF = 128 * NCHUNK * 72;
  const size_t needF = (size_t)QKV_ELE * 2 + partF + 9216 + 131072 + 128;
  if (ws_size < needF * 4) {
    fill_sentinel<<<dim3((out_size + 255) / 256), dim3(256), 0, stream>>>(out, out_size);
    return;
  }
  float* qkv    = ws;
  float* agg    = qkv + QKV_ELE;
  float* part   = agg + QKV_ELE;
  float* vkbuf  = part + partF;       // 128*72
  float* Mp     = vkbuf + 9216;       // 4*128*256
  float* shiftb = Mp + 131072;        // 128

  k1_qkv<<<dim3(1536), 256, 0, stream>>>(x, wqkv, qkv);
  k2_dwpw<<<dim3(4, 8, 192), 256, 0, stream>>>(qkv, wdw, wpw, agg);
  k3_vk<<<dim3(NCHUNK, 128), 256, 0, stream>>>(qkv, agg, part);
  k3b_sum<<<dim3(128), 128, 0, stream>>>(part, vkbuf);
  k3c_M<<<dim3(512), 256, 0, stream>>>(wproj, vkbuf, gamma, beta, mean, var, Mp, shiftb);
  k4_proj<<<dim3(128, 4), 256, 0, stream>>>(qkv, agg, vkbuf, Mp, shiftb, out);
}

// Round 4
// 195.385 us; speedup vs baseline: 1.4192x; 1.2093x over previous
//
#include <hip/hip_runtime.h>

#define BB 4
#define CIN 128
#define T3 384
#define HH 128
#define WW 128
#define NPIX 16384
#define QKV_ELE (BB*T3*NPIX)   // 25165824 floats per big buffer
#define NCHUNK 16
#define PB 132

typedef __attribute__((ext_vector_type(8))) short bf16x8;
typedef __attribute__((ext_vector_type(4))) float f32x4;

#define HI_SEL 0x07060302u
#define LO_SEL 0x05040100u

// split fp32 -> (bf16 hi, bf16 lo) RNE, packed (hi<<16)|lo
__device__ __forceinline__ unsigned splitpack(float x) {
  unsigned u = __float_as_uint(x);
  unsigned hb = (u + 0x7fffu + ((u >> 16) & 1u)) >> 16;
  float lo = x - __uint_as_float(hb << 16);
  unsigned ul = __float_as_uint(lo);
  unsigned lb = (ul + 0x7fffu + ((ul >> 16) & 1u)) >> 16;
  return (hb << 16) | (lb & 0xffffu);
}

// ============================================================================
// K0: pre-pack wqkv into the exact per-(co-tile m, k-chunk c) LDS image:
// img[(m*4+c)*4096 + kgrp*1024 + co*8 + k7], element = splitpack(W[co][ci])
// ============================================================================
__global__ __launch_bounds__(256) void k0_wprep(const float* __restrict__ wqkv,
                                                unsigned* __restrict__ wimg) {
  int id = blockIdx.x * 256 + threadIdx.x;   // 0..49151
  int img = id >> 12;
  int inner = id & 4095;
  int kgrp = inner >> 10;
  int rem = inner & 1023;
  int co = rem >> 3;
  int k7 = rem & 7;
  int m = img >> 2, c = img & 3;
  int cog = m * 128 + co;
  int ci = c * 32 + kgrp * 8 + k7;
  wimg[id] = splitpack(wqkv[cog * 128 + ci]);
}

// ============================================================================
// K1: qkv = W(384x128) @ X(128x16384/b) via split-bf16 MFMA (3-pass hh+hl+lh).
// Block 256thr=4 waves, tile 128co x 128n, waves 2x2 (64co x 64n each).
// LDS: packed-u32 (hi|lo) layout, off = (kk>>3)*1028 + n*8 + (kk&7).
// Frag: 2x ds_read_b128 + v_perm unpack. XCD-grouped grid (as before).
// ============================================================================
__global__ __launch_bounds__(256) void k1_qkv_mfma(const float* __restrict__ x,
                                                   const unsigned* __restrict__ wimg,
                                                   float* __restrict__ qkv) {
  __shared__ __align__(16) unsigned Xp[4 * 1028];
  __shared__ __align__(16) unsigned Wp[4 * 1028];
  const int t = threadIdx.x;
  const int p = blockIdx.x;            // 0..1535
  const int qd = p / 24;
  const int r_ = p - qd * 24;
  const int m = r_ >> 3;               // co-tile 0..2
  const int tt = qd * 8 + (r_ & 7);    // 0..511
  const int n0 = (tt & 127) * 128;
  const int b = tt >> 7;
  const float* xb = x + (size_t)b * CIN * NPIX + n0;

  const int l = t & 63;
  const int w = t >> 6;
  const int g = l >> 4;      // 0..3
  const int lc = l & 15;
  const int ch = w >> 1;     // co half
  const int nh = w & 1;      // n half

  const int su = t >> 5;     // staging k-sub 0..7
  const int sT = t & 31;     // staging n-quad 0..31

  f32x4 acc[4][4];
  #pragma unroll
  for (int i = 0; i < 4; ++i)
    #pragma unroll
    for (int j = 0; j < 4; ++j) acc[i][j] = (f32x4){0.f, 0.f, 0.f, 0.f};

  for (int c = 0; c < 4; ++c) {
    {  // stage W (straight copy of pre-packed image)
      const uint4* wsrc = (const uint4*)(wimg + (((m << 2) | c) << 12));
      #pragma unroll
      for (int r = 0; r < 4; ++r) {
        uint4 v = wsrc[r * 256 + t];
        *(uint4*)&Wp[r * 1028 + (t << 2)] = v;
      }
    }
    {  // stage X: load 4 rows (kk=su*4+r), splitpack, in-register transpose, 4x b128
      const float* xrow = xb + (size_t)(c * 32 + su * 4) * NPIX + sT * 4;
      unsigned pk[4][4];
      #pragma unroll
      for (int r = 0; r < 4; ++r) {
        float4 v = *(const float4*)(xrow + (size_t)r * NPIX);
        pk[r][0] = splitpack(v.x); pk[r][1] = splitpack(v.y);
        pk[r][2] = splitpack(v.z); pk[r][3] = splitpack(v.w);
      }
      const int xbase = (su >> 1) * 1028 + (su & 1) * 4;
      #pragma unroll
      for (int i = 0; i < 4; ++i) {
        uint4 q = make_uint4(pk[0][i], pk[1][i], pk[2][i], pk[3][i]);
        *(uint4*)&Xp[xbase + (sT * 4 + i) * 8] = q;
      }
    }
    __syncthreads();

    bf16x8 bh[4], bl[4];
    #pragma unroll
    for (int ng = 0; ng < 4; ++ng) {
      const int n8 = (nh * 64 + ng * 16 + lc) * 8;
      uint4 qa = *(const uint4*)&Xp[g * 1028 + n8];
      uint4 qb = *(const uint4*)&Xp[g * 1028 + n8 + 4];
      unsigned* ph = (unsigned*)&bh[ng];
      unsigned* pl = (unsigned*)&bl[ng];
      ph[0] = __builtin_amdgcn_perm(qa.y, qa.x, HI_SEL);
      ph[1] = __builtin_amdgcn_perm(qa.w, qa.z, HI_SEL);
      ph[2] = __builtin_amdgcn_perm(qb.y, qb.x, HI_SEL);
      ph[3] = __builtin_amdgcn_perm(qb.w, qb.z, HI_SEL);
      pl[0] = __builtin_amdgcn_perm(qa.y, qa.x, LO_SEL);
      pl[1] = __builtin_amdgcn_perm(qa.w, qa.z, LO_SEL);
      pl[2] = __builtin_amdgcn_perm(qb.y, qb.x, LO_SEL);
      pl[3] = __builtin_amdgcn_perm(qb.w, qb.z, LO_SEL);
    }
    #pragma unroll
    for (int cg = 0; cg < 4; ++cg) {
      const int c8 = (ch * 64 + cg * 16 + lc) * 8;
      uint4 qa = *(const uint4*)&Wp[g * 1028 + c8];
      uint4 qb = *(const uint4*)&Wp[g * 1028 + c8 + 4];
      bf16x8 ah, al;
      unsigned* ph = (unsigned*)&ah;
      unsigned* pl = (unsigned*)&al;
      ph[0] = __builtin_amdgcn_perm(qa.y, qa.x, HI_SEL);
      ph[1] = __builtin_amdgcn_perm(qa.w, qa.z, HI_SEL);
      ph[2] = __builtin_amdgcn_perm(qb.y, qb.x, HI_SEL);
      ph[3] = __builtin_amdgcn_perm(qb.w, qb.z, HI_SEL);
      pl[0] = __builtin_amdgcn_perm(qa.y, qa.x, LO_SEL);
      pl[1] = __builtin_amdgcn_perm(qa.w, qa.z, LO_SEL);
      pl[2] = __builtin_amdgcn_perm(qb.y, qb.x, LO_SEL);
      pl[3] = __builtin_amdgcn_perm(qb.w, qb.z, LO_SEL);
      #pragma unroll
      for (int ng = 0; ng < 4; ++ng) {
        acc[cg][ng] = __builtin_amdgcn_mfma_f32_16x16x32_bf16(ah, bh[ng], acc[cg][ng], 0, 0, 0);
        acc[cg][ng] = __builtin_amdgcn_mfma_f32_16x16x32_bf16(ah, bl[ng], acc[cg][ng], 0, 0, 0);
        acc[cg][ng] = __builtin_amdgcn_mfma_f32_16x16x32_bf16(al, bh[ng], acc[cg][ng], 0, 0, 0);
      }
    }
    __syncthreads();
  }
  // epilogue: D row = co = g*4+reg (per 16-group), col = n = lc
  #pragma unroll
  for (int cg = 0; cg < 4; ++cg) {
    const size_t corow = (size_t)b * T3 + m * 128 + ch * 64 + cg * 16 + g * 4;
    #pragma unroll
    for (int ng = 0; ng < 4; ++ng) {
      const int nn = n0 + nh * 64 + ng * 16 + lc;
      #pragma unroll
      for (int rr = 0; rr < 4; ++rr)
        qkv[(corow + rr) * NPIX + nn] = acc[cg][ng][rr];
    }
  }
}

// ============================================================================
// K2: agg = grouped_pw( dw5x5(qkv) ).  (unchanged)
// ============================================================================
#define PIN 40
#define PDW 36
__global__ __launch_bounds__(256) void k2_dwpw(const float* __restrict__ qkv,
                                               const float* __restrict__ wdw,
                                               const float* __restrict__ wpw,
                                               float* __restrict__ agg) {
  __shared__ __align__(16) float smem[8 * 20 * PIN];
  __shared__ float wds[8][25];
  __shared__ float wps[64];
  const int t = threadIdx.x;
  const int x0 = blockIdx.x * 32;
  const int y0 = blockIdx.y * 16;
  const int bg = blockIdx.z;
  const int b = bg / 48;
  const int g = bg % 48;
  const float* src = qkv + ((size_t)b * T3 + g * 8) * NPIX;

  for (int id = t; id < 1440; id += 256) {
    int ch = id / 180;
    int rem = id - ch * 180;
    int ry = rem / 9;
    int rx4 = (rem - ry * 9) * 4;
    int gy = y0 + ry - 2;
    int gx = x0 + rx4 - 2;
    float4 v = make_float4(0.f, 0.f, 0.f, 0.f);
    if ((unsigned)gy < (unsigned)HH) {
      const float* rp = src + (size_t)ch * NPIX + gy * WW + gx;
      if (gx >= 0 && gx + 3 < WW) {
        v = *(const float4*)rp;
      } else {
        if ((unsigned)gx < (unsigned)WW) v.x = rp[0];
        if ((unsigned)(gx + 1) < (unsigned)WW) v.y = rp[1];
        if ((unsigned)(gx + 2) < (unsigned)WW) v.z = rp[2];
        if ((unsigned)(gx + 3) < (unsigned)WW) v.w = rp[3];
      }
    }
    *(float4*)&smem[ch * (20 * PIN) + ry * PIN + rx4] = v;
  }
  for (int idx = t; idx < 200; idx += 256)
    wds[idx / 25][idx % 25] = wdw[(size_t)g * 200 + idx];
  if (t < 64) wps[t] = wpw[g * 64 + t];
  __syncthreads();

  const int ch = t >> 5;
  const int xq = t & 7;
  const int yg = (t >> 3) & 3;
  float rbw[8][8];
  {
    const float* base = &smem[ch * (20 * PIN) + (yg * 4) * PIN + xq * 4];
    #pragma unroll
    for (int rr = 0; rr < 8; ++rr) {
      float4 u0 = *(const float4*)(base + rr * PIN);
      float4 u1 = *(const float4*)(base + rr * PIN + 4);
      rbw[rr][0] = u0.x; rbw[rr][1] = u0.y; rbw[rr][2] = u0.z; rbw[rr][3] = u0.w;
      rbw[rr][4] = u1.x; rbw[rr][5] = u1.y; rbw[rr][6] = u1.z; rbw[rr][7] = u1.w;
    }
  }
  float dacc[4][4];
  #pragma unroll
  for (int jy = 0; jy < 4; ++jy)
    #pragma unroll
    for (int jx = 0; jx < 4; ++jx) dacc[jy][jx] = 0.f;
  #pragma unroll
  for (int ky = 0; ky < 5; ++ky)
    #pragma unroll
    for (int kx = 0; kx < 5; ++kx) {
      float wv = wds[ch][ky * 5 + kx];
      #pragma unroll
      for (int jy = 0; jy < 4; ++jy)
        #pragma unroll
        for (int jx = 0; jx < 4; ++jx)
          dacc[jy][jx] += wv * rbw[jy + ky][jx + kx];
    }
  __syncthreads();

  #pragma unroll
  for (int jy = 0; jy < 4; ++jy) {
    float4 o = make_float4(dacc[jy][0], dacc[jy][1], dacc[jy][2], dacc[jy][3]);
    *(float4*)&smem[ch * (16 * PDW) + (yg * 4 + jy) * PDW + xq * 4] = o;
  }
  __syncthreads();

  float* dst = agg + ((size_t)b * T3 + g * 8) * NPIX + (size_t)y0 * WW + x0;
  #pragma unroll
  for (int pp = 0; pp < 2; ++pp) {
    int pix = t + pp * 256;
    int py = pix >> 5;
    int px = pix & 31;
    float dv[8];
    #pragma unroll
    for (int ic = 0; ic < 8; ++ic) dv[ic] = smem[ic * (16 * PDW) + py * PDW + px];
    #pragma unroll
    for (int oc = 0; oc < 8; ++oc) {
      float s = 0.f;
      #pragma unroll
      for (int ic = 0; ic < 8; ++ic) s += wps[oc * 8 + ic] * dv[ic];
      dst[(size_t)oc * NPIX + py * WW + px] = s;
    }
  }
}

// ============================================================================
// K3: vk partials (unchanged)
// ============================================================================
__global__ __launch_bounds__(256) void k3_vk(const float* __restrict__ qkv,
                                             const float* __restrict__ agg,
                                             float* __restrict__ part) {
  const int chunk = blockIdx.x;
  const int bh = blockIdx.y;
  const int b = bh >> 5;
  const int h = bh & 31;
  const int hh = h & 15;
  const float* base = (h < 16 ? qkv : agg) + ((size_t)b * T3 + hh * 24) * NPIX;
  const float* kb = base + 8 * NPIX;
  const float* vb = base + 16 * NPIX;
  const int t = threadIdx.x;
  const int wv = t >> 6;
  const int lane = t & 63;
  const int d0 = wv * 2;

  float accA[8], accB[8], accS[8];
  #pragma unroll
  for (int e = 0; e < 8; ++e) { accA[e] = 0.f; accB[e] = 0.f; accS[e] = 0.f; }

  int p = chunk * (NPIX / NCHUNK) + lane;
  for (int it = 0; it < (NPIX / NCHUNK / 64); ++it, p += 64) {
    float kvv[8];
    #pragma unroll
    for (int e = 0; e < 8; ++e) kvv[e] = fmaxf(kb[(size_t)e * NPIX + p], 0.f);
    float vA = vb[(size_t)d0 * NPIX + p];
    float vB = vb[(size_t)(d0 + 1) * NPIX + p];
    #pragma unroll
    for (int e = 0; e < 8; ++e) { accA[e] += vA * kvv[e]; accB[e] += vB * kvv[e]; }
    if (wv == 0) {
      #pragma unroll
      for (int e = 0; e < 8; ++e) accS[e] += kvv[e];
    }
  }
  #pragma unroll
  for (int e = 0; e < 8; ++e) {
    #pragma unroll
    for (int m = 1; m < 64; m <<= 1) {
      accA[e] += __shfl_xor(accA[e], m);
      accB[e] += __shfl_xor(accB[e], m);
    }
  }
  if (wv == 0) {
    #pragma unroll
    for (int e = 0; e < 8; ++e)
      #pragma unroll
      for (int m = 1; m < 64; m <<= 1) accS[e] += __shfl_xor(accS[e], m);
  }
  if (lane == 0) {
    float* pr = part + ((size_t)bh * NCHUNK + chunk) * 72;
    #pragma unroll
    for (int e = 0; e < 8; ++e) {
      pr[d0 * 8 + e] = accA[e];
      pr[(d0 + 1) * 8 + e] = accB[e];
    }
    if (wv == 0) {
      #pragma unroll
      for (int e = 0; e < 8; ++e) pr[64 + e] = accS[e];
    }
  }
}

__global__ __launch_bounds__(128) void k3b_sum(const float* __restrict__ part,
                                               float* __restrict__ vk) {
  const int bh = blockIdx.x;
  const int j = threadIdx.x;
  if (j < 72) {
    float s = 0.f;
    #pragma unroll
    for (int c = 0; c < NCHUNK; ++c) s += part[((size_t)bh * NCHUNK + c) * 72 + j];
    vk[(size_t)bh * 72 + j] = s;
  }
}

__global__ __launch_bounds__(256) void k3c_M(const float* __restrict__ wproj,
                                             const float* __restrict__ vk,
                                             const float* __restrict__ gamma,
                                             const float* __restrict__ beta,
                                             const float* __restrict__ mean,
                                             const float* __restrict__ var,
                                             float* __restrict__ Mp,
                                             float* __restrict__ shiftb) {
  int id = blockIdx.x * 256 + threadIdx.x;
  int b = id >> 15;
  int rem = id & 32767;
  int co = rem >> 8;
  int c = rem & 255;
  int h = c >> 3, e = c & 7;
  float inv = gamma[co] * rsqrtf(var[co] + 1e-5f);
  const float* wrow = wproj + (size_t)co * 256 + h * 8;
  const float* vkc = vk + ((size_t)b * 32 + h) * 72 + e;
  float s = 0.f;
  #pragma unroll
  for (int d = 0; d < 8; ++d) s += wrow[d] * vkc[d * 8];
  Mp[id] = inv * s;
  if (b == 0 && c == 0) shiftb[co] = beta[co] - mean[co] * inv;
}

// ============================================================================
// K4: out = M' @ Q' + shift  (unchanged fp32)
// ============================================================================
__global__ __launch_bounds__(256) void k4_proj(const float* __restrict__ qkv,
                                               const float* __restrict__ agg,
                                               const float* __restrict__ vk,
                                               const float* __restrict__ Mp,
                                               const float* __restrict__ shiftb,
                                               float* __restrict__ out) {
  __shared__ __align__(16) float As[32 * 128];
  __shared__ __align__(16) float Bs[32 * PB];
  const int t = threadIdx.x;
  const int n0 = blockIdx.x * 128;
  const int b = blockIdx.y;
  float acc[8][8];
  #pragma unroll
  for (int i = 0; i < 8; ++i)
    #pragma unroll
    for (int j = 0; j < 8; ++j) acc[i][j] = 0.f;
  const int co_g = t >> 4;
  const int n_g = t & 15;

  for (int cidx = 0; cidx < 8; ++cidx) {
    const int c0 = cidx * 32;
    const int h0 = cidx * 4;
    {
      const int c_l = t >> 3;
      const int nq = t & 7;
      const int h = h0 + (c_l >> 3);
      const int e = c_l & 7;
      const float* srcb = (h < 16 ? qkv : agg);
      const float* src = srcb + ((size_t)b * T3 + (h & 15) * 24 + e) * NPIX + n0 + nq * 16;
      float4 v0 = ((const float4*)src)[0];
      float4 v1 = ((const float4*)src)[1];
      float4 v2 = ((const float4*)src)[2];
      float4 v3 = ((const float4*)src)[3];
      v0.x = fmaxf(v0.x, 0.f); v0.y = fmaxf(v0.y, 0.f); v0.z = fmaxf(v0.z, 0.f); v0.w = fmaxf(v0.w, 0.f);
      v1.x = fmaxf(v1.x, 0.f); v1.y = fmaxf(v1.y, 0.f); v1.z = fmaxf(v1.z, 0.f); v1.w = fmaxf(v1.w, 0.f);
      v2.x = fmaxf(v2.x, 0.f); v2.y = fmaxf(v2.y, 0.f); v2.z = fmaxf(v2.z, 0.f); v2.w = fmaxf(v2.w, 0.f);
      v3.x = fmaxf(v3.x, 0.f); v3.y = fmaxf(v3.y, 0.f); v3.z = fmaxf(v3.z, 0.f); v3.w = fmaxf(v3.w, 0.f);
      float* brow = &Bs[c_l * PB + nq * 16];
      ((float4*)brow)[0] = v0;
      ((float4*)brow)[1] = v1;
      ((float4*)brow)[2] = v2;
      ((float4*)brow)[3] = v3;
    }
    {
      const int co_l = t >> 1;
      const int kq = t & 1;
      const float* mrow = Mp + ((size_t)b * 128 + co_l) * 256 + c0 + kq * 16;
      #pragma unroll
      for (int rr = 0; rr < 4; ++rr) {
        float4 v = ((const float4*)mrow)[rr];
        int k = kq * 16 + rr * 4;
        As[(k + 0) * 128 + co_l] = v.x;
        As[(k + 1) * 128 + co_l] = v.y;
        As[(k + 2) * 128 + co_l] = v.z;
        As[(k + 3) * 128 + co_l] = v.w;
      }
    }
    __syncthreads();
    #pragma unroll
    for (int ss = 0; ss < 2; ++ss) {
      int s = t + ss * 256;
      int hj = s >> 7;
      int px = s & 127;
      const float* vkrow = vk + ((size_t)(b * 32) + h0 + hj) * 72 + 64;
      float q8[8];
      float den = 1e-15f;
      #pragma unroll
      for (int e = 0; e < 8; ++e) {
        q8[e] = Bs[(hj * 8 + e) * PB + px];
        den += vkrow[e] * q8[e];
      }
      float rden = 1.0f / den;
      #pragma unroll
      for (int e = 0; e < 8; ++e) Bs[(hj * 8 + e) * PB + px] = q8[e] * rden;
    }
    __syncthreads();
    #pragma unroll
    for (int kk = 0; kk < 32; ++kk) {
      float4 a0 = *(const float4*)&As[kk * 128 + co_g * 4];
      float4 a1 = *(const float4*)&As[kk * 128 + 64 + co_g * 4];
      float4 b0 = *(const float4*)&Bs[kk * PB + n_g * 4];
      float4 b1 = *(const float4*)&Bs[kk * PB + 64 + n_g * 4];
      float av[8] = {a0.x, a0.y, a0.z, a0.w, a1.x, a1.y, a1.z, a1.w};
      float bv[8] = {b0.x, b0.y, b0.z, b0.w, b1.x, b1.y, b1.z, b1.w};
      #pragma unroll
      for (int i = 0; i < 8; ++i)
        #pragma unroll
        for (int j = 0; j < 8; ++j) acc[i][j] += av[i] * bv[j];
    }
    __syncthreads();
  }
  #pragma unroll
  for (int i = 0; i < 8; ++i) {
    int co = (i < 4) ? (co_g * 4 + i) : (64 + co_g * 4 + i - 4);
    float sh = shiftb[co];
    float* orow = out + ((size_t)b * 128 + co) * NPIX + n0;
    float4 o0 = make_float4(acc[i][0] + sh, acc[i][1] + sh, acc[i][2] + sh, acc[i][3] + sh);
    float4 o1 = make_float4(acc[i][4] + sh, acc[i][5] + sh, acc[i][6] + sh, acc[i][7] + sh);
    *(float4*)&orow[n_g * 4] = o0;
    *(float4*)&orow[64 + n_g * 4] = o1;
  }
}

__global__ void fill_sentinel(float* o, int n) {
  int i = blockIdx.x * 256 + threadIdx.x;
  if (i < n) o[i] = 12345.0f;
}

extern "C" void kernel_launch(void* const* d_in, const int* in_sizes, int n_in,
                              void* d_out, int out_size, void* d_ws, size_t ws_size,
                              hipStream_t stream) {
  const float* x     = (const float*)d_in[0];
  const float* wqkv  = (const float*)d_in[1];
  const float* wdw   = (const float*)d_in[2];
  const float* wpw   = (const float*)d_in[3];
  const float* wproj = (const float*)d_in[4];
  const float* gamma = (const float*)d_in[5];
  const float* beta  = (const float*)d_in[6];
  const float* mean  = (const float*)d_in[7];
  const float* var   = (const float*)d_in[8];
  float* out = (float*)d_out;
  float* ws = (float*)d_ws;

  const size_t partF = 128 * NCHUNK * 72;
  const size_t needF = (size_t)QKV_ELE * 2 + partF + 9216 + 131072 + 128 + 49152;
  if (ws_size < needF * 4) {
    fill_sentinel<<<dim3((out_size + 255) / 256), dim3(256), 0, stream>>>(out, out_size);
    return;
  }
  float* qkv    = ws;
  float* agg    = qkv + QKV_ELE;
  float* part   = agg + QKV_ELE;
  float* vkbuf  = part + partF;
  float* Mp     = vkbuf + 9216;
  float* shiftb = Mp + 131072;
  unsigned* wimg = (unsigned*)(shiftb + 128);   // 49152 u32

  k0_wprep<<<dim3(192), 256, 0, stream>>>(wqkv, wimg);
  k1_qkv_mfma<<<dim3(1536), 256, 0, stream>>>(x, wimg, qkv);
  k2_dwpw<<<dim3(4, 8, 192), 256, 0, stream>>>(qkv, wdw, wpw, agg);
  k3_vk<<<dim3(NCHUNK, 128), 256, 0, stream>>>(qkv, agg, part);
  k3b_sum<<<dim3(128), 128, 0, stream>>>(part, vkbuf);
  k3c_M<<<dim3(512), 256, 0, stream>>>(wproj, vkbuf, gamma, beta, mean, var, Mp, shiftb);
  k4_proj<<<dim3(128, 4), 256, 0, stream>>>(qkv, agg, vkbuf, Mp, shiftb, out);
}

// Round 6
// 156.228 us; speedup vs baseline: 1.7750x; 1.2506x over previous
//
#include <hip/hip_runtime.h>

#define BB 4
#define CIN 128
#define T3 384
#define HH 128
#define WW 128
#define NPIX 16384
#define QKV_ELE (BB*T3*NPIX)
#define NCHUNK 16

// MFMA packed-image geometry: per 32-k chunk: 4 k-groups x (hi plane 520 + lo
// plane 520) u32; column (kgrp, n) = 4 contiguous u32 (8 bf16) at
// kgrp*1040 + plane*520 + n*4.  Section = 4160 u32 = 1040 uint4.
#define SEC 4160
#define KGP 1040
#define PLN 520

typedef __attribute__((ext_vector_type(8))) short bf16x8;
typedef __attribute__((ext_vector_type(4))) float f32x4;

// split fp32 -> (bf16 hi, bf16 lo) RNE, packed (hi<<16)|lo
__device__ __forceinline__ unsigned splitpack(float x) {
  unsigned u = __float_as_uint(x);
  unsigned hb = (u + 0x7fffu + ((u >> 16) & 1u)) >> 16;
  float lo = x - __uint_as_float(hb << 16);
  unsigned ul = __float_as_uint(lo);
  unsigned lb = (ul + 0x7fffu + ((ul >> 16) & 1u)) >> 16;
  return (hb << 16) | (lb & 0xffffu);
}

__device__ __forceinline__ void packpair(float a, float b, unsigned& hi, unsigned& lo) {
  unsigned p0 = splitpack(a), p1 = splitpack(b);
  hi = (p1 & 0xffff0000u) | (p0 >> 16);
  lo = (p1 << 16) | (p0 & 0xffffu);
}

// ============================================================================
// K0: pre-pack wqkv into MFMA image: per (co-tile m, k-chunk c) one SEC.
// ============================================================================
__global__ __launch_bounds__(256) void k0_wprep(const float* __restrict__ wqkv,
                                                unsigned* __restrict__ wimg) {
  int id = blockIdx.x * 256 + threadIdx.x;   // 0..24575
  int i = id & 3;
  int co = (id >> 2) & 127;
  int kgrp = (id >> 9) & 3;
  int c = (id >> 11) & 3;
  int m = id >> 13;                          // 0..2
  int ci = c * 32 + kgrp * 8 + 2 * i;
  const float* wrow = wqkv + (size_t)(m * 128 + co) * 128 + ci;
  unsigned hi, lo;
  packpair(wrow[0], wrow[1], hi, lo);
  size_t base = (size_t)(m * 4 + c) * SEC + kgrp * KGP + co * 4 + i;
  wimg[base] = hi;
  wimg[base + PLN] = lo;
}

// ============================================================================
// K1: qkv = W @ X via split-bf16 MFMA (3-pass). Column-gather staging,
// plane layout (conflict-free LDS). XCD-grouped grid.
// ============================================================================
__global__ __launch_bounds__(256) void k1_qkv_mfma(const float* __restrict__ x,
                                                   const unsigned* __restrict__ wimg,
                                                   float* __restrict__ qkv) {
  __shared__ __align__(16) unsigned Xp[4 * KGP];
  __shared__ __align__(16) unsigned Wp[4 * KGP];
  const int t = threadIdx.x;
  const int p = blockIdx.x;            // 0..1535
  const int qd = p / 24;
  const int r_ = p - qd * 24;
  const int m = r_ >> 3;               // co-tile 0..2
  const int tt = qd * 8 + (r_ & 7);    // 0..511
  const int n0 = (tt & 127) * 128;
  const int b = tt >> 7;
  const float* xb = x + (size_t)b * CIN * NPIX + n0;

  const int l = t & 63;
  const int w = t >> 6;
  const int g = l >> 4;      // k-group for frag reads
  const int lc = l & 15;
  const int ch = w >> 1;     // co half
  const int nh = w & 1;      // n half

  const int kg = t >> 6;     // staging: wave = k-group
  const int nn_ = t & 63;

  f32x4 acc[4][4];
  #pragma unroll
  for (int i = 0; i < 4; ++i)
    #pragma unroll
    for (int j = 0; j < 4; ++j) acc[i][j] = (f32x4){0.f, 0.f, 0.f, 0.f};

  for (int c = 0; c < 4; ++c) {
    {  // stage W (straight copy of pre-packed image): 1040 uint4 -> 5 passes
      const uint4* wsrc = (const uint4*)(wimg + (size_t)(m * 4 + c) * SEC);
      uint4* wdst = (uint4*)Wp;
      #pragma unroll
      for (int r = 0; r < 5; ++r) {
        int idx = t + r * 256;
        if (idx < 1040) wdst[idx] = wsrc[idx];
      }
    }
    {  // stage X: column-gather, pack in registers, conflict-free b128 writes
      const float* colbase = xb + (size_t)(c * 32 + kg * 8) * NPIX;
      #pragma unroll
      for (int half = 0; half < 2; ++half) {
        int n = nn_ + half * 64;
        const float* colp = colbase + n;
        unsigned hp[4], lp[4];
        #pragma unroll
        for (int i = 0; i < 4; ++i)
          packpair(colp[(size_t)(2 * i) * NPIX], colp[(size_t)(2 * i + 1) * NPIX],
                   hp[i], lp[i]);
        *(uint4*)&Xp[kg * KGP + n * 4] = make_uint4(hp[0], hp[1], hp[2], hp[3]);
        *(uint4*)&Xp[kg * KGP + PLN + n * 4] = make_uint4(lp[0], lp[1], lp[2], lp[3]);
      }
    }
    __syncthreads();

    bf16x8 bh[4], bl[4];
    #pragma unroll
    for (int ng = 0; ng < 4; ++ng) {
      const int nb = (nh * 64 + ng * 16 + lc) * 4;
      bh[ng] = *(const bf16x8*)&Xp[g * KGP + nb];
      bl[ng] = *(const bf16x8*)&Xp[g * KGP + PLN + nb];
    }
    #pragma unroll
    for (int cg = 0; cg < 4; ++cg) {
      const int cb = (ch * 64 + cg * 16 + lc) * 4;
      bf16x8 ah = *(const bf16x8*)&Wp[g * KGP + cb];
      bf16x8 al = *(const bf16x8*)&Wp[g * KGP + PLN + cb];
      #pragma unroll
      for (int ng = 0; ng < 4; ++ng) {
        acc[cg][ng] = __builtin_amdgcn_mfma_f32_16x16x32_bf16(ah, bh[ng], acc[cg][ng], 0, 0, 0);
        acc[cg][ng] = __builtin_amdgcn_mfma_f32_16x16x32_bf16(ah, bl[ng], acc[cg][ng], 0, 0, 0);
        acc[cg][ng] = __builtin_amdgcn_mfma_f32_16x16x32_bf16(al, bh[ng], acc[cg][ng], 0, 0, 0);
      }
    }
    __syncthreads();
  }
  #pragma unroll
  for (int cg = 0; cg < 4; ++cg) {
    const size_t corow = (size_t)b * T3 + m * 128 + ch * 64 + cg * 16 + g * 4;
    #pragma unroll
    for (int ng = 0; ng < 4; ++ng) {
      const int nn = n0 + nh * 64 + ng * 16 + lc;
      #pragma unroll
      for (int rr = 0; rr < 4; ++rr)
        qkv[(corow + rr) * NPIX + nn] = acc[cg][ng][rr];
    }
  }
}

// ============================================================================
// K2: agg = grouped_pw( dw5x5(qkv) ). XCD-chunked swizzle (one (b,g) slab per
// XCD -> halo from L2). Aligned staging [x0-4,x0+40), PIN=44/PLCH=888
// (2-way banks max). Row-streamed dw. smem reused for dw output.
// ============================================================================
#define PIN2 44
#define PLCH 888   // channel plane stride: 888 mod 32 = 24 -> 2-way banks
#define PDW 36
__global__ __launch_bounds__(256) void k2_dwpw(const float* __restrict__ qkv,
                                               const float* __restrict__ wdw,
                                               const float* __restrict__ wpw,
                                               float* __restrict__ agg) {
  __shared__ __align__(16) float smem[8 * PLCH];  // 7104 floats; reused as dws[8*16*PDW]
  __shared__ float wds[8][25];
  __shared__ float wps[64];
  const int t = threadIdx.x;
  const int p = blockIdx.x;                 // 0..6143
  const int L = (p & 7) * 768 + (p >> 3);   // chunked: 24 full (b,g) slabs per XCD
  const int z = L >> 5;                     // (b,g) 0..191
  const int rem = L & 31;
  const int x0 = (rem & 3) * 32;
  const int y0 = (rem >> 2) * 16;
  const int b = z / 48;
  const int g = z % 48;
  const float* src = qkv + ((size_t)b * T3 + g * 8) * NPIX;

  // stage: 8ch x 20 rows x 11 aligned float4 (cols x0-4 .. x0+39)
  for (int id = t; id < 1760; id += 256) {
    int ch = id / 220;
    int r2 = id - ch * 220;
    int ry = r2 / 11;
    int c4 = r2 - ry * 11;
    int gy = y0 + ry - 2;
    int gx = x0 + c4 * 4 - 4;
    float4 v = make_float4(0.f, 0.f, 0.f, 0.f);
    if ((unsigned)gy < (unsigned)HH && (unsigned)gx < (unsigned)WW)
      v = *(const float4*)(src + (size_t)ch * NPIX + gy * WW + gx);
    *(float4*)&smem[ch * PLCH + ry * PIN2 + c4 * 4] = v;
  }
  for (int idx = t; idx < 200; idx += 256)
    wds[idx / 25][idx % 25] = wdw[(size_t)g * 200 + idx];
  if (t < 64) wps[t] = wpw[g * 64 + t];
  __syncthreads();

  // depthwise 5x5, row-streamed: thread -> (ch, 4 x-cols, 4 y-rows)
  const int ch = t >> 5;
  const int xq = t & 7;
  const int yg = (t >> 3) & 3;
  float dacc[4][4];
  #pragma unroll
  for (int jy = 0; jy < 4; ++jy)
    #pragma unroll
    for (int jx = 0; jx < 4; ++jx) dacc[jy][jx] = 0.f;
  {
    const float* bcol = &smem[ch * PLCH + (yg * 4) * PIN2 + xq * 4];
    #pragma unroll
    for (int r = 0; r < 8; ++r) {
      float4 u0 = *(const float4*)(bcol + r * PIN2);
      float4 u1 = *(const float4*)(bcol + r * PIN2 + 4);
      float4 u2 = *(const float4*)(bcol + r * PIN2 + 8);
      float vals[12] = {u0.x, u0.y, u0.z, u0.w, u1.x, u1.y, u1.z, u1.w,
                        u2.x, u2.y, u2.z, u2.w};
      #pragma unroll
      for (int jy = 0; jy < 4; ++jy) {
        int ky = r - jy;
        if (ky < 0 || ky > 4) continue;
        #pragma unroll
        for (int kx = 0; kx < 5; ++kx) {
          float wv = wds[ch][ky * 5 + kx];
          #pragma unroll
          for (int jx = 0; jx < 4; ++jx)
            dacc[jy][jx] += wv * vals[jx + kx + 2];
        }
      }
    }
  }
  __syncthreads();   // all ins reads done -> safe to overwrite smem

  #pragma unroll
  for (int jy = 0; jy < 4; ++jy) {
    float4 o = make_float4(dacc[jy][0], dacc[jy][1], dacc[jy][2], dacc[jy][3]);
    *(float4*)&smem[ch * (16 * PDW) + (yg * 4 + jy) * PDW + xq * 4] = o;
  }
  __syncthreads();

  // grouped pointwise 8x8
  float* dst = agg + ((size_t)b * T3 + g * 8) * NPIX + (size_t)y0 * WW + x0;
  #pragma unroll
  for (int pp = 0; pp < 2; ++pp) {
    int pix = t + pp * 256;
    int py = pix >> 5;
    int px = pix & 31;
    float dv[8];
    #pragma unroll
    for (int ic = 0; ic < 8; ++ic) dv[ic] = smem[ic * (16 * PDW) + py * PDW + px];
    #pragma unroll
    for (int oc = 0; oc < 8; ++oc) {
      float s = 0.f;
      #pragma unroll
      for (int ic = 0; ic < 8; ++ic) s += wps[oc * 8 + ic] * dv[ic];
      dst[(size_t)oc * NPIX + py * WW + px] = s;
    }
  }
}

// ============================================================================
// K3: vk partials (unchanged), k3b sum (unchanged)
// ============================================================================
__global__ __launch_bounds__(256) void k3_vk(const float* __restrict__ qkv,
                                             const float* __restrict__ agg,
                                             float* __restrict__ part) {
  const int chunk = blockIdx.x;
  const int bh = blockIdx.y;
  const int b = bh >> 5;
  const int h = bh & 31;
  const int hh = h & 15;
  const float* base = (h < 16 ? qkv : agg) + ((size_t)b * T3 + hh * 24) * NPIX;
  const float* kb = base + 8 * NPIX;
  const float* vb = base + 16 * NPIX;
  const int t = threadIdx.x;
  const int wv = t >> 6;
  const int lane = t & 63;
  const int d0 = wv * 2;

  float accA[8], accB[8], accS[8];
  #pragma unroll
  for (int e = 0; e < 8; ++e) { accA[e] = 0.f; accB[e] = 0.f; accS[e] = 0.f; }

  int p = chunk * (NPIX / NCHUNK) + lane;
  for (int it = 0; it < (NPIX / NCHUNK / 64); ++it, p += 64) {
    float kvv[8];
    #pragma unroll
    for (int e = 0; e < 8; ++e) kvv[e] = fmaxf(kb[(size_t)e * NPIX + p], 0.f);
    float vA = vb[(size_t)d0 * NPIX + p];
    float vB = vb[(size_t)(d0 + 1) * NPIX + p];
    #pragma unroll
    for (int e = 0; e < 8; ++e) { accA[e] += vA * kvv[e]; accB[e] += vB * kvv[e]; }
    if (wv == 0) {
      #pragma unroll
      for (int e = 0; e < 8; ++e) accS[e] += kvv[e];
    }
  }
  #pragma unroll
  for (int e = 0; e < 8; ++e) {
    #pragma unroll
    for (int m = 1; m < 64; m <<= 1) {
      accA[e] += __shfl_xor(accA[e], m);
      accB[e] += __shfl_xor(accB[e], m);
    }
  }
  if (wv == 0) {
    #pragma unroll
    for (int e = 0; e < 8; ++e)
      #pragma unroll
      for (int m = 1; m < 64; m <<= 1) accS[e] += __shfl_xor(accS[e], m);
  }
  if (lane == 0) {
    float* pr = part + ((size_t)bh * NCHUNK + chunk) * 72;
    #pragma unroll
    for (int e = 0; e < 8; ++e) {
      pr[d0 * 8 + e] = accA[e];
      pr[(d0 + 1) * 8 + e] = accB[e];
    }
    if (wv == 0) {
      #pragma unroll
      for (int e = 0; e < 8; ++e) pr[64 + e] = accS[e];
    }
  }
}

__global__ __launch_bounds__(128) void k3b_sum(const float* __restrict__ part,
                                               float* __restrict__ vk) {
  const int bh = blockIdx.x;
  const int j = threadIdx.x;
  if (j < 72) {
    float s = 0.f;
    #pragma unroll
    for (int c = 0; c < NCHUNK; ++c) s += part[((size_t)bh * NCHUNK + c) * 72 + j];
    vk[(size_t)bh * 72 + j] = s;
  }
}

// ============================================================================
// K3c: M' = BN-folded Wproj x vk, written directly as packed MFMA image:
// per (b, cidx) one SEC.  Also shift[co].
// ============================================================================
__global__ __launch_bounds__(256) void k3c_M(const float* __restrict__ wproj,
                                             const float* __restrict__ vk,
                                             const float* __restrict__ gamma,
                                             const float* __restrict__ beta,
                                             const float* __restrict__ mean,
                                             const float* __restrict__ var,
                                             unsigned* __restrict__ Mimg,
                                             float* __restrict__ shiftb) {
  int id = blockIdx.x * 256 + threadIdx.x;   // 0..65535
  int i = id & 3;
  int co = (id >> 2) & 127;
  int kgrp = (id >> 9) & 3;
  int cidx = (id >> 11) & 7;
  int b = id >> 14;
  int h = cidx * 4 + kgrp;
  float inv = gamma[co] * rsqrtf(var[co] + 1e-5f);
  const float* wrow = wproj + (size_t)co * 256 + h * 8;
  const float* vkc = vk + ((size_t)b * 32 + h) * 72;
  float s0 = 0.f, s1 = 0.f;
  #pragma unroll
  for (int d = 0; d < 8; ++d) {
    float wv = wrow[d];
    s0 += wv * vkc[d * 8 + 2 * i];
    s1 += wv * vkc[d * 8 + 2 * i + 1];
  }
  unsigned hi, lo;
  packpair(inv * s0, inv * s1, hi, lo);
  size_t base = (size_t)(b * 8 + cidx) * SEC + kgrp * KGP + co * 4 + i;
  Mimg[base] = hi;
  Mimg[base + PLN] = lo;
  if (b == 0 && cidx == 0 && kgrp == 0 && i == 0)
    shiftb[co] = beta[co] - mean[co] * inv;
}

// ============================================================================
// K4: out = M' @ Q' + shift via split-bf16 MFMA. Column-gather staging:
// thread owns (head, n) column -> 8 q loads, den in registers, pack, 2 b128.
// ============================================================================
__global__ __launch_bounds__(256) void k4_mfma(const float* __restrict__ qkv,
                                               const float* __restrict__ agg,
                                               const float* __restrict__ vk,
                                               const unsigned* __restrict__ Mimg,
                                               const float* __restrict__ shiftb,
                                               float* __restrict__ out) {
  __shared__ __align__(16) unsigned Ap[4 * KGP];
  __shared__ __align__(16) unsigned Bp[4 * KGP];
  const int t = threadIdx.x;
  const int n0 = blockIdx.x * 128;
  const int b = blockIdx.y;

  const int l = t & 63;
  const int w = t >> 6;
  const int g = l >> 4;
  const int lc = l & 15;
  const int ch = w >> 1;
  const int nh = w & 1;

  const int hj = t >> 6;     // staging: wave = k-group = head offset
  const int nn_ = t & 63;

  f32x4 acc[4][4];
  #pragma unroll
  for (int i = 0; i < 4; ++i)
    #pragma unroll
    for (int j = 0; j < 4; ++j) acc[i][j] = (f32x4){0.f, 0.f, 0.f, 0.f};

  for (int cidx = 0; cidx < 8; ++cidx) {
    {  // stage A = M' image: 1040 uint4 -> 5 passes
      const uint4* asrc = (const uint4*)(Mimg + (size_t)(b * 8 + cidx) * SEC);
      uint4* adst = (uint4*)Ap;
      #pragma unroll
      for (int r = 0; r < 5; ++r) {
        int idx = t + r * 256;
        if (idx < 1040) adst[idx] = asrc[idx];
      }
    }
    {  // stage B = Q' columns (relu, den, rescale, pack) — all in registers
      const int h = cidx * 4 + hj;
      const float* srcb = (h < 16 ? qkv : agg) +
                          ((size_t)b * T3 + (h & 15) * 24) * NPIX + n0;
      const float* vkr = vk + ((size_t)b * 32 + h) * 72 + 64;
      float vv[8];
      #pragma unroll
      for (int e = 0; e < 8; ++e) vv[e] = vkr[e];
      #pragma unroll
      for (int half = 0; half < 2; ++half) {
        int n = nn_ + half * 64;
        float q[8];
        float den = 1e-15f;
        #pragma unroll
        for (int e = 0; e < 8; ++e) {
          q[e] = fmaxf(srcb[(size_t)e * NPIX + n], 0.f);
          den += vv[e] * q[e];
        }
        float rd = 1.0f / den;
        unsigned hp[4], lp[4];
        #pragma unroll
        for (int i = 0; i < 4; ++i)
          packpair(q[2 * i] * rd, q[2 * i + 1] * rd, hp[i], lp[i]);
        *(uint4*)&Bp[hj * KGP + n * 4] = make_uint4(hp[0], hp[1], hp[2], hp[3]);
        *(uint4*)&Bp[hj * KGP + PLN + n * 4] = make_uint4(lp[0], lp[1], lp[2], lp[3]);
      }
    }
    __syncthreads();

    bf16x8 bh[4], bl[4];
    #pragma unroll
    for (int ng = 0; ng < 4; ++ng) {
      const int nb = (nh * 64 + ng * 16 + lc) * 4;
      bh[ng] = *(const bf16x8*)&Bp[g * KGP + nb];
      bl[ng] = *(const bf16x8*)&Bp[g * KGP + PLN + nb];
    }
    #pragma unroll
    for (int cg = 0; cg < 4; ++cg) {
      const int cb = (ch * 64 + cg * 16 + lc) * 4;
      bf16x8 ah = *(const bf16x8*)&Ap[g * KGP + cb];
      bf16x8 al = *(const bf16x8*)&Ap[g * KGP + PLN + cb];
      #pragma unroll
      for (int ng = 0; ng < 4; ++ng) {
        acc[cg][ng] = __builtin_amdgcn_mfma_f32_16x16x32_bf16(ah, bh[ng], acc[cg][ng], 0, 0, 0);
        acc[cg][ng] = __builtin_amdgcn_mfma_f32_16x16x32_bf16(ah, bl[ng], acc[cg][ng], 0, 0, 0);
        acc[cg][ng] = __builtin_amdgcn_mfma_f32_16x16x32_bf16(al, bh[ng], acc[cg][ng], 0, 0, 0);
      }
    }
    __syncthreads();
  }
  #pragma unroll
  for (int cg = 0; cg < 4; ++cg) {
    const int cobase = ch * 64 + cg * 16 + g * 4;
    #pragma unroll
    for (int ng = 0; ng < 4; ++ng) {
      const int nn = n0 + nh * 64 + ng * 16 + lc;
      #pragma unroll
      for (int rr = 0; rr < 4; ++rr) {
        int co = cobase + rr;
        out[((size_t)b * 128 + co) * NPIX + nn] = acc[cg][ng][rr] + shiftb[co];
      }
    }
  }
}

__global__ void fill_sentinel(float* o, int n) {
  int i = blockIdx.x * 256 + threadIdx.x;
  if (i < n) o[i] = 12345.0f;
}

extern "C" void kernel_launch(void* const* d_in, const int* in_sizes, int n_in,
                              void* d_out, int out_size, void* d_ws, size_t ws_size,
                              hipStream_t stream) {
  const float* x     = (const float*)d_in[0];
  const float* wqkv  = (const float*)d_in[1];
  const float* wdw   = (const float*)d_in[2];
  const float* wpw   = (const float*)d_in[3];
  const float* wproj = (const float*)d_in[4];
  const float* gamma = (const float*)d_in[5];
  const float* beta  = (const float*)d_in[6];
  const float* mean  = (const float*)d_in[7];
  const float* var   = (const float*)d_in[8];
  float* out = (float*)d_out;
  float* ws = (float*)d_ws;

  const size_t partF = 128 * NCHUNK * 72;        // 147456
  const size_t mimgF = 32 * SEC;                 // 133120
  const size_t wimgF = 12 * SEC;                 // 49920
  const size_t needF = (size_t)QKV_ELE * 2 + partF + 9216 + 128 + mimgF + wimgF;
  if (ws_size < needF * 4) {
    fill_sentinel<<<dim3((out_size + 255) / 256), dim3(256), 0, stream>>>(out, out_size);
    return;
  }
  float* qkv    = ws;
  float* agg    = qkv + QKV_ELE;
  float* part   = agg + QKV_ELE;
  float* vkbuf  = part + partF;
  float* shiftb = vkbuf + 9216;
  unsigned* Mimg = (unsigned*)(shiftb + 128);
  unsigned* wimg = Mimg + mimgF;

  k0_wprep<<<dim3(96), 256, 0, stream>>>(wqkv, wimg);
  k1_qkv_mfma<<<dim3(1536), 256, 0, stream>>>(x, wimg, qkv);
  k2_dwpw<<<dim3(6144), 256, 0, stream>>>(qkv, wdw, wpw, agg);
  k3_vk<<<dim3(NCHUNK, 128), 256, 0, stream>>>(qkv, agg, part);
  k3b_sum<<<dim3(128), 128, 0, stream>>>(part, vkbuf);
  k3c_M<<<dim3(256), 256, 0, stream>>>(wproj, vkbuf, gamma, beta, mean, var, Mimg, shiftb);
  k4_mfma<<<dim3(128, 4), 256, 0, stream>>>(qkv, agg, vkbuf, Mimg, shiftb, out);
}